// Round 20
// baseline (497.719 us; speedup 1.0000x reference)
//
#include <hip/hip_runtime.h>
#include <hip/hip_bf16.h>

// nGPT-style transformer layer, MI355X. Round 19: W_O projection moved to the
// 256^2 pipelined kernel with split-K=2 (bf16 partials summed in lerp1 via
// Tt2), same recipe as Wv. Rest = round-18 best-known (495.7 us).
// B=4 T=2048 dm=1024 H=16 di=64.
//
// Workspace arena (peak 210 MiB). Aliasing is ORDER-SENSITIVE; launch order in
// kernel_launch is the contract. xb (144MiB) is DEAD after step 1 (Qb
// aliases). tbufa/tbufb (48/64MiB) live in dead-QKVb region, dead before uv.

#define B_   4
#define T_   2048
#define DM   1024
#define H_   16
#define DI   64
#define NROW (B_ * T_)   // 8192

using bf16 = __hip_bfloat16;
typedef __attribute__((ext_vector_type(8))) short bfrag;   // 8 bf16 (4 VGPR)
typedef __attribute__((ext_vector_type(4))) float f4;

#define EXPB 46.166241f   // 32 * log2(e): sdpa-scale x log2e, folded into Q

__device__ __forceinline__ float ldf(const float* p) { return *p; }
__device__ __forceinline__ float ldf(const bf16* p)  { return __bfloat162float(*p); }
__device__ __forceinline__ void  stf(float* p, float v) { *p = v; }
__device__ __forceinline__ void  stf(bf16* p, float v)  { *p = __float2bfloat16(v); }

__device__ __forceinline__ unsigned short bfbits(float a) {
    bf16 h = __float2bfloat16(a);
    return __builtin_bit_cast(unsigned short, h);
}
__device__ __forceinline__ unsigned pk2(float a, float b) {    // RNE (converts)
    return (unsigned)bfbits(a) | ((unsigned)bfbits(b) << 16);
}
// truncation pack: hi16(a) | hi16(b)<<16 in ONE v_perm_b32 (P in [0,1]).
__device__ __forceinline__ unsigned pk2t(float a, float b) {
    return __builtin_amdgcn_perm(__builtin_bit_cast(unsigned, b),
                                 __builtin_bit_cast(unsigned, a), 0x07060302u);
}

// fast exp2: single v_exp_f32
__device__ __forceinline__ float fexp2(float x) {
    return __builtin_amdgcn_exp2f(x);
}

// vectorized 4-element loads (contiguous per thread)
__device__ __forceinline__ void ld4(const float* p, float* o) {
    float4 v = *(const float4*)p;
    o[0] = v.x; o[1] = v.y; o[2] = v.z; o[3] = v.w;
}
__device__ __forceinline__ void ld4(const bf16* p, float* o) {
    ushort4 v = *(const ushort4*)p;
    o[0] = __builtin_bit_cast(float, (unsigned)v.x << 16);
    o[1] = __builtin_bit_cast(float, (unsigned)v.y << 16);
    o[2] = __builtin_bit_cast(float, (unsigned)v.z << 16);
    o[3] = __builtin_bit_cast(float, (unsigned)v.w << 16);
}

__device__ __forceinline__ float wave_sum(float v) {
#pragma unroll
    for (int off = 32; off; off >>= 1) v += __shfl_xor(v, off, 64);
    return v;
}

__device__ __forceinline__ float block_sum(float v) {
    __shared__ float sm[4];
    int lane = threadIdx.x & 63, w = threadIdx.x >> 6;
    v = wave_sum(v);
    __syncthreads();
    if (lane == 0) sm[w] = v;
    __syncthreads();
    return sm[0] + sm[1] + sm[2] + sm[3];
}

// async global->LDS, 16B per lane; LDS dest = wave-uniform base + lane*16
typedef __attribute__((address_space(1))) const void g_void;
typedef __attribute__((address_space(3))) void l_void;
__device__ __forceinline__ void gl_lds(const void* g, void* l) {
    __builtin_amdgcn_global_load_lds((g_void*)g, (l_void*)l, 16, 0, 0);
}

// ---------------------------------------------------------------------------
// f32 -> bf16 convert, 8 elems/thread. n must be a multiple of 2048.
// ---------------------------------------------------------------------------
__global__ __launch_bounds__(256)
void f32_to_bf16_k(const float* __restrict__ in, bf16* __restrict__ out, long n)
{
    long i = ((long)blockIdx.x * 256 + threadIdx.x) * 8;
    if (i >= n) return;
    float4 a = *(const float4*)(in + i);
    float4 b = *(const float4*)(in + i + 4);
    union { bfrag f; unsigned u[4]; } o;
    o.u[0] = pk2(a.x, a.y); o.u[1] = pk2(a.z, a.w);
    o.u[2] = pk2(b.x, b.y); o.u[3] = pk2(b.z, b.w);
    *(bfrag*)(out + i) = o.f;
}

// ---------------------------------------------------------------------------
// C = A * B^T, 256x256 tile, BK=64, 8 waves (2M x 4N), 128KB LDS dbuf.
// 2-cluster schedule: counted vmcnt(8), (row&7) chunk-XOR swizzle,
// setprio around MFMA clusters. LD = leading dim of A and B (>= K);
// blockIdx.z advances A/B by K elements (split-K) and C by sCz elements.
// M,N %256==0, K %64==0, K>=128.
// ---------------------------------------------------------------------------
template <typename TC>
__global__ __launch_bounds__(512, 2)
void gemm_bf16_256(const bf16* __restrict__ A, const bf16* __restrict__ Bm,
                   TC* __restrict__ C, int M, int N, int K, int LD, long sCz)
{
    A  += (long)blockIdx.z * K;
    Bm += (long)blockIdx.z * K;
    C  += (long)blockIdx.z * sCz;

    __shared__ bf16 lds[2][2][256 * 64];   // 128 KiB
    const int tid  = threadIdx.x;
    const int w    = tid >> 6, lane = tid & 63;
    const int g    = lane >> 4, c = lane & 15;
    const int m0   = blockIdx.y * 256, n0 = blockIdx.x * 256;
    const int wm   = w & 1, wn = w >> 1;          // 2M x 4N wave grid
    const int srow8 = lane >> 3;                  // 0..7
    const int swz   = 8 * ((lane & 7) ^ srow8);   // pre-swizzled source chunk
    const int cx    = c & 7;

    f4 acc[8][4] = {{{0,0,0,0}}};

    const int NT = K >> 6;

    auto STAGE = [&](int buf, int t) {
        int k0 = t << 6;
#pragma unroll
        for (int i = 0; i < 4; i++) {
            int rb = w * 32 + i * 8;              // 8 rows per gl_lds
            gl_lds(A  + (long)(m0 + rb + srow8) * LD + k0 + swz, &lds[buf][0][rb * 64]);
            gl_lds(Bm + (long)(n0 + rb + srow8) * LD + k0 + swz, &lds[buf][1][rb * 64]);
        }
    };

    STAGE(0, 0);
    STAGE(1, 1);
    asm volatile("s_waitcnt vmcnt(8)" ::: "memory");
    __builtin_amdgcn_s_barrier();

    for (int t = 0; t < NT; t++) {
        const bf16* bufA = &lds[t & 1][0][0];
        const bf16* bufB = &lds[t & 1][1][0];

        bfrag a0[4][2], b0[4][2];
#pragma unroll
        for (int mi = 0; mi < 4; mi++)
#pragma unroll
            for (int kk = 0; kk < 2; kk++)
                a0[mi][kk] = *(const bfrag*)(bufA + (wm * 128 + mi * 16 + c) * 64
                                                  + 8 * ((4 * kk + g) ^ cx));
#pragma unroll
        for (int ni = 0; ni < 4; ni++)
#pragma unroll
            for (int kk = 0; kk < 2; kk++)
                b0[ni][kk] = *(const bfrag*)(bufB + (wn * 64 + ni * 16 + c) * 64
                                                  + 8 * ((4 * kk + g) ^ cx));
        asm volatile("s_waitcnt lgkmcnt(0)" ::: "memory");
        __builtin_amdgcn_sched_barrier(0);
        __builtin_amdgcn_s_setprio(1);
#pragma unroll
        for (int mi = 0; mi < 4; mi++)
#pragma unroll
            for (int ni = 0; ni < 4; ni++) {
                acc[mi][ni] = __builtin_amdgcn_mfma_f32_16x16x32_bf16(
                    a0[mi][0], b0[ni][0], acc[mi][ni], 0, 0, 0);
                acc[mi][ni] = __builtin_amdgcn_mfma_f32_16x16x32_bf16(
                    a0[mi][1], b0[ni][1], acc[mi][ni], 0, 0, 0);
            }
        __builtin_amdgcn_s_setprio(0);

        bfrag a1[4][2];
#pragma unroll
        for (int mi = 0; mi < 4; mi++)
#pragma unroll
            for (int kk = 0; kk < 2; kk++)
                a1[mi][kk] = *(const bfrag*)(bufA + (wm * 128 + (mi + 4) * 16 + c) * 64
                                                  + 8 * ((4 * kk + g) ^ cx));
        asm volatile("s_waitcnt lgkmcnt(0)" ::: "memory");
        __builtin_amdgcn_sched_barrier(0);
        __builtin_amdgcn_s_setprio(1);
#pragma unroll
        for (int mi = 0; mi < 4; mi++)
#pragma unroll
            for (int ni = 0; ni < 4; ni++) {
                acc[mi + 4][ni] = __builtin_amdgcn_mfma_f32_16x16x32_bf16(
                    a1[mi][0], b0[ni][0], acc[mi + 4][ni], 0, 0, 0);
                acc[mi + 4][ni] = __builtin_amdgcn_mfma_f32_16x16x32_bf16(
                    a1[mi][1], b0[ni][1], acc[mi + 4][ni], 0, 0, 0);
            }
        __builtin_amdgcn_s_setprio(0);

        __builtin_amdgcn_s_barrier();
        if (t + 2 < NT) {
            STAGE(t & 1, t + 2);
            asm volatile("s_waitcnt vmcnt(8)" ::: "memory");
        } else if (t + 1 < NT) {
            asm volatile("s_waitcnt vmcnt(0)" ::: "memory");
        }
        __builtin_amdgcn_s_barrier();
    }

#pragma unroll
    for (int mi = 0; mi < 8; mi++)
#pragma unroll
        for (int ni = 0; ni < 4; ni++) {
            long row = m0 + wm * 128 + mi * 16 + 4 * g;
            long col = n0 + wn * 64 + ni * 16 + c;
#pragma unroll
            for (int r = 0; r < 4; r++)
                stf(&C[(row + r) * N + col], acc[mi][ni][r]);
        }
}

// ---------------------------------------------------------------------------
// RoPE v2 + per-row L2 norm + sqk*sqrt(dm); QKVb bf16 layout [row][h*192+e].
// Block = (h, b, 64-wide t-tile); 4 waves x 16 rows. V staged in LDS [64][66]
// then written as 16 contiguous t-elems per thread -> coalesced Vt.
// Qb carries sdpa sqrt(dm)=32 AND log2e (exp2 path in attn).
// ---------------------------------------------------------------------------
__global__ __launch_bounds__(256)
void rope_norm_qk(const bf16* __restrict__ QKVb, const float* __restrict__ sqk,
                  bf16* __restrict__ Qb, bf16* __restrict__ Kb, bf16* __restrict__ Vt)
{
    __shared__ unsigned short vbuf[64][66];   // pad 66 -> <=4-way on gather

    int bid  = blockIdx.x;                // 0..2047
    int h    = bid >> 7;                  // / (B_*32)
    int rem  = bid & 127;
    int b    = rem >> 5;
    int tile = rem & 31;
    int w    = threadIdx.x >> 6;
    int lane = threadIdx.x & 63;

    int   j       = lane & 31;
    // inv_rev = 10000^(-j/32) / (2*pi);  log2(10000)/32 = 0.41524101
    float inv_rev = fexp2(-(float)j * 0.41524101f) * 0.15915494f;
    float se      = sqk[h * 64 + lane] * 32.f;   // sqk * sqrt(dm)

#pragma unroll 1
    for (int i = 0; i < 16; i++) {
        int tl = i * 4 + w;               // 0..63
        int t  = tile * 64 + tl;
        long row = (long)b * T_ + t;
        const bf16* base = QKVb + row * 3072 + h * 192;
        float q = ldf(base + lane);
        float k = ldf(base + 64 + lane);
        unsigned short vb = ((const unsigned short*)base)[128 + lane];

        float ar = (float)t * inv_rev;
        ar = ar - floorf(ar);                       // revolutions in [0,1)
        float s  = __builtin_amdgcn_sinf(ar);
        float cc = __builtin_amdgcn_cosf(ar);

        float qp = __shfl_xor(q, 32, 64);
        float kp = __shfl_xor(k, 32, 64);
        float sgn = (lane < 32) ? -1.f : 1.f;
        float qr = q * cc + sgn * qp * s;
        float kr = k * cc + sgn * kp * s;

        float qs = wave_sum(qr * qr);
        float ks = wave_sum(kr * kr);

        long idx = ((long)h * NROW + row) * 64 + lane;
        Qb[idx] = __float2bfloat16(qr * rsqrtf(qs) * se * EXPB);  // 32*log2e
        Kb[idx] = __float2bfloat16(kr * rsqrtf(ks) * se);
        vbuf[tl][lane] = vb;
    }
    __syncthreads();

    // V transpose write: thread -> (d = tid>>2, 16 t's at seg*16)
    int d   = threadIdx.x >> 2;
    int seg = threadIdx.x & 3;
    union { bfrag f; unsigned short s[8]; } o0, o1;
#pragma unroll
    for (int jj = 0; jj < 8; jj++) {
        o0.s[jj] = vbuf[seg * 16 + jj][d];
        o1.s[jj] = vbuf[seg * 16 + 8 + jj][d];
    }
    bf16* dst = Vt + ((long)(h * B_ + b) * 64 + d) * T_ + tile * 64 + seg * 16;
    *(bfrag*)dst       = o0.f;
    *(bfrag*)(dst + 8) = o1.f;
}

// ---------------------------------------------------------------------------
// MFMA flash attention, exp2 fixed-shift softmax (C-init = -EXPB), paired
// q-tiles. 8-wave blocks (512 thr), K/V LDS staging shared by 8 waves.
// Per-wave ranges differ by <=1 iteration (nA = 2*blk + (w>=4)); actA/actB
// guards wave-uniform. Heavy/light blk interleave; XCD swizzle.
// ---------------------------------------------------------------------------
__global__ __launch_bounds__(512)
void attn_mfma(const bf16* __restrict__ Qb, const bf16* __restrict__ Kb,
               const bf16* __restrict__ Vt, bf16* __restrict__ O)
{
    __shared__ bf16 kv[2][2][64 * 64];    // [buf][K|V][row*64 + chunk-swizzled]

    int orig   = blockIdx.x;              // 0..511
    int xcd    = orig & 7;
    int rest   = orig >> 3;               // 0..63
    int bh     = xcd * 8 + (rest & 7);    // 8 (b,h) per XCD -> 4MiB K/V in L2
    int blkraw = rest >> 3;               // 0..7
    int blk    = (blkraw & 1) ? (7 - (blkraw >> 1)) : (blkraw >> 1);
    int w      = threadIdx.x >> 6;        // 0..7
    int pr     = blk * 8 + w;             // 0..63
    int h = bh >> 2, b = bh & 3;

    int lane = threadIdx.x & 63;
    int g = lane >> 4, c = lane & 15;

    const bf16* kbase = Kb + ((long)h * NROW + (long)b * T_) * 64;
    const bf16* vbase = Vt + (long)(h * B_ + b) * 64 * (long)T_;

    int q0A = pr * 16, q0B = (127 - pr) * 16;
    const bf16* qbA = Qb + ((long)h * NROW + (long)b * T_ + q0A) * 64;
    const bf16* qbB = Qb + ((long)h * NROW + (long)b * T_ + q0B) * 64;
    bfrag qfA0 = *(const bfrag*)(qbA + (long)c * 64 + 8 * g);
    bfrag qfA1 = *(const bfrag*)(qbA + (long)c * 64 + 32 + 8 * g);
    bfrag qfB0 = *(const bfrag*)(qbB + (long)c * 64 + 8 * g);
    bfrag qfB1 = *(const bfrag*)(qbB + (long)c * 64 + 32 + 8 * g);

    const f4 CINIT = {-EXPB, -EXPB, -EXPB, -EXPB};

    f4 otA[4] = {{0,0,0,0},{0,0,0,0},{0,0,0,0},{0,0,0,0}};
    f4 otB[4] = {{0,0,0,0},{0,0,0,0},{0,0,0,0},{0,0,0,0}};
    float lA = 0.f, lB = 0.f;

    const int nA = pr >> 2;               // 2*blk + (w>=4)
    const int nB = 31 - nA;
    const int KTblk = 31 - 2 * blk;       // block-uniform loop bound (max nB)
    int qgA = q0A + c, qgB = q0B + c;

    const int srow8  = lane >> 3;                 // 0..7
    const int swz    = 8 * ((lane & 7) ^ srow8);  // swizzled source chunk

    auto STAGE = [&](int buf, int kt) {
        int k0 = kt * 64;
        int row = w * 8 + srow8;                  // 8 waves cover 64 rows
        gl_lds(kbase + (long)(k0 + row) * 64 + swz, &kv[buf][0][w * 8 * 64]);
        gl_lds(vbase + (long)row * T_ + k0 + swz,   &kv[buf][1][w * 8 * 64]);
    };

    STAGE(0, 0);
    __syncthreads();

    const int cx = c & 7;

    for (int kt = 0; kt <= KTblk; kt++) {
        int buf = kt & 1;
        if (kt < KTblk) STAGE(buf ^ 1, kt + 1);

        const bf16* Kl = &kv[buf][0][0];
        const bf16* Vl = &kv[buf][1][0];
        int k0 = kt * 64;
        bool actA = (kt <= nA);           // wave-uniform
        bool actB = (kt <= nB);           // wave-uniform
        unsigned wvA[8], wvB[8];

        if (actA || actB) {
#pragma unroll
            for (int kb = 0; kb < 4; kb++) {
                const bf16* kr = Kl + (16 * kb + c) * 64;
                bfrag ka = *(const bfrag*)(kr + 8 * (g ^ cx));
                bfrag kc = *(const bfrag*)(kr + 8 * ((g | 4) ^ cx));

                if (actB) {
                    f4 sB = __builtin_amdgcn_mfma_f32_16x16x32_bf16(ka, qfB0, CINIT, 0, 0, 0);
                    sB = __builtin_amdgcn_mfma_f32_16x16x32_bf16(kc, qfB1, sB, 0, 0, 0);
                    if (kt == nB) {
#pragma unroll
                        for (int r = 0; r < 4; r++)
                            if (k0 + 16 * kb + 4 * g + r > qgB) sB[r] = -1e30f;
                    }
                    float eB0 = fexp2(sB[0]), eB1 = fexp2(sB[1]);
                    float eB2 = fexp2(sB[2]), eB3 = fexp2(sB[3]);
                    lB += (eB0 + eB1) + (eB2 + eB3);
                    wvB[2 * kb]     = pk2t(eB0, eB1);
                    wvB[2 * kb + 1] = pk2t(eB2, eB3);
                }

                if (actA) {
                    f4 sA = __builtin_amdgcn_mfma_f32_16x16x32_bf16(ka, qfA0, CINIT, 0, 0, 0);
                    sA = __builtin_amdgcn_mfma_f32_16x16x32_bf16(kc, qfA1, sA, 0, 0, 0);
                    if (kt == nA) {
#pragma unroll
                        for (int r = 0; r < 4; r++)
                            if (k0 + 16 * kb + 4 * g + r > qgA) sA[r] = -1e30f;
                    }
                    float eA0 = fexp2(sA[0]), eA1 = fexp2(sA[1]);
                    float eA2 = fexp2(sA[2]), eA3 = fexp2(sA[3]);
                    lA += (eA0 + eA1) + (eA2 + eA3);
                    wvA[2 * kb]     = pk2t(eA0, eA1);
                    wvA[2 * kb + 1] = pk2t(eA2, eA3);
                }
            }

            // PV: two 32-key halves; B-frag = P^T via lane exchange; V from LDS
#pragma unroll
            for (int p = 0; p < 2; p++) {
                int s0l = c + 32 * (g & 1), s1l = s0l + 16;
                bool hi = (g >= 2);

                union { bfrag f; unsigned u[4]; } pfB, pfA;
                if (actB) {
                    unsigned Bb0 = (unsigned)__shfl((int)wvB[4 * p + 0], s0l, 64);
                    unsigned Bb1 = (unsigned)__shfl((int)wvB[4 * p + 1], s0l, 64);
                    unsigned Bb2 = (unsigned)__shfl((int)wvB[4 * p + 2], s0l, 64);
                    unsigned Bb3 = (unsigned)__shfl((int)wvB[4 * p + 3], s0l, 64);
                    unsigned Bb4 = (unsigned)__shfl((int)wvB[4 * p + 0], s1l, 64);
                    unsigned Bb5 = (unsigned)__shfl((int)wvB[4 * p + 1], s1l, 64);
                    unsigned Bb6 = (unsigned)__shfl((int)wvB[4 * p + 2], s1l, 64);
                    unsigned Bb7 = (unsigned)__shfl((int)wvB[4 * p + 3], s1l, 64);
                    pfB.u[0] = hi ? Bb2 : Bb0;
                    pfB.u[1] = hi ? Bb3 : Bb1;
                    pfB.u[2] = hi ? Bb6 : Bb4;
                    pfB.u[3] = hi ? Bb7 : Bb5;
                }
                if (actA) {
                    unsigned Ab0 = (unsigned)__shfl((int)wvA[4 * p + 0], s0l, 64);
                    unsigned Ab1 = (unsigned)__shfl((int)wvA[4 * p + 1], s0l, 64);
                    unsigned Ab2 = (unsigned)__shfl((int)wvA[4 * p + 2], s0l, 64);
                    unsigned Ab3 = (unsigned)__shfl((int)wvA[4 * p + 3], s0l, 64);
                    unsigned Ab4 = (unsigned)__shfl((int)wvA[4 * p + 0], s1l, 64);
                    unsigned Ab5 = (unsigned)__shfl((int)wvA[4 * p + 1], s1l, 64);
                    unsigned Ab6 = (unsigned)__shfl((int)wvA[4 * p + 2], s1l, 64);
                    unsigned Ab7 = (unsigned)__shfl((int)wvA[4 * p + 3], s1l, 64);
                    pfA.u[0] = hi ? Ab2 : Ab0;
                    pfA.u[1] = hi ? Ab3 : Ab1;
                    pfA.u[2] = hi ? Ab6 : Ab4;
                    pfA.u[3] = hi ? Ab7 : Ab5;
                }

#pragma unroll
                for (int dblk = 0; dblk < 4; dblk++) {
                    bfrag vf = *(const bfrag*)(Vl + (16 * dblk + c) * 64
                                                  + 8 * (((p << 2) | g) ^ cx));
                    if (actB)
                        otB[dblk] = __builtin_amdgcn_mfma_f32_16x16x32_bf16(vf, pfB.f, otB[dblk], 0, 0, 0);
                    if (actA)
                        otA[dblk] = __builtin_amdgcn_mfma_f32_16x16x32_bf16(vf, pfA.f, otA[dblk], 0, 0, 0);
                }
            }
        }
        __syncthreads();
    }

    lA += __shfl_xor(lA, 16, 64); lA += __shfl_xor(lA, 32, 64);
    lB += __shfl_xor(lB, 16, 64); lB += __shfl_xor(lB, 32, 64);

    float invA = 1.f / lA, invB = 1.f / lB;
    long orowA = (long)(b * T_ + q0A + c) * DM + h * 64;
    long orowB = (long)(b * T_ + q0B + c) * DM + h * 64;
#pragma unroll
    for (int dblk = 0; dblk < 4; dblk++)
#pragma unroll
        for (int r = 0; r < 4; r++) {
            O[orowA + 16 * dblk + 4 * g + r] = __float2bfloat16(otA[dblk][r] * invA);
            O[orowB + 16 * dblk + 4 * g + r] = __float2bfloat16(otB[dblk][r] * invB);
        }
}

// ---------------------------------------------------------------------------
// Out = justnorm(A + lr*(Bn - A)); t-input = Tt (+ Tt2 if non-null, summed).
// Vectorized: thread handles 4 contiguous elems at tid*4.
// ---------------------------------------------------------------------------
template <typename TX, typename TT>
__global__ __launch_bounds__(256)
void lerp_norm(const TX* __restrict__ X, const TT* __restrict__ Tt,
               const TT* __restrict__ Tt2, const float* __restrict__ alpha,
               float ascale, float* __restrict__ OutF, bf16* __restrict__ OutB)
{
    long row = blockIdx.x;
    int t4 = threadIdx.x * 4;
    const TX* xr = X  + row * DM + t4;
    const TT* tr = Tt + row * DM + t4;

    float xs[4], ts[4];
    ld4(xr, xs);
    ld4(tr, ts);
    if (Tt2) {
        float t2[4];
        ld4(Tt2 + row * DM + t4, t2);
#pragma unroll
        for (int i = 0; i < 4; i++) ts[i] += t2[i];
    }
    float sx = 0.f, st = 0.f;
#pragma unroll
    for (int i = 0; i < 4; i++) { sx += xs[i] * xs[i]; st += ts[i] * ts[i]; }
    sx = block_sum(sx);
    st = block_sum(st);
    float ix = rsqrtf(sx), it = rsqrtf(st);

    float4 al = *(const float4*)(alpha + t4);
    float av[4] = {al.x, al.y, al.z, al.w};
    float ys[4], sy = 0.f;
#pragma unroll
    for (int i = 0; i < 4; i++) {
        float a  = xs[i] * ix;
        float bn = ts[i] * it;
        float lr = fabsf(av[i] * ascale);
        ys[i] = a + lr * (bn - a);
        sy += ys[i] * ys[i];
    }
    sy = block_sum(sy);
    float iy = rsqrtf(sy);
#pragma unroll
    for (int i = 0; i < 4; i++) ys[i] *= iy;

    if (OutF) *(float4*)(OutF + row * DM + t4) = make_float4(ys[0], ys[1], ys[2], ys[3]);
    if (OutB) {
        uint2 o;
        o.x = pk2(ys[0], ys[1]);
        o.y = pk2(ys[2], ys[3]);
        *(uint2*)(OutB + row * DM + t4) = o;
    }
}

// ---------------------------------------------------------------------------
// tn = justnorm(suv*32*uv_row[8192]); res = u*silu(v). Vectorized single-pass.
// ---------------------------------------------------------------------------
__global__ __launch_bounds__(256)
void mlp_act(const bf16* __restrict__ UV, const float* __restrict__ suv,
             bf16* __restrict__ R)
{
    long row = blockIdx.x;
    const bf16* ur = UV + row * 8192;
    int t8 = threadIdx.x * 8;

    float f[4][8];
    float ss = 0.f;
#pragma unroll
    for (int ch = 0; ch < 4; ch++) {
        bfrag d = *(const bfrag*)(ur + ch * 2048 + t8);
        const float4* sp = (const float4*)(suv + ch * 2048 + t8);
        float4 s0 = sp[0], s1 = sp[1];
        float sv[8] = {s0.x, s0.y, s0.z, s0.w, s1.x, s1.y, s1.z, s1.w};
#pragma unroll
        for (int e = 0; e < 8; e++) {
            unsigned short us = __builtin_bit_cast(unsigned short, (short)d[e]);
            float v = __builtin_bit_cast(float, (unsigned)us << 16) * sv[e] * 32.f;
            f[ch][e] = v;
            ss += v * v;
        }
    }
    ss = block_sum(ss);
    float inv = rsqrtf(ss);

#pragma unroll
    for (int ch = 0; ch < 2; ch++) {
        union { bfrag f; unsigned u[4]; } o;
#pragma unroll
        for (int e = 0; e < 8; e += 2) {
            float u0 = f[ch][e]     * inv, u1 = f[ch][e + 1]     * inv;
            float v0 = f[ch + 2][e] * inv, v1 = f[ch + 2][e + 1] * inv;
            float r0 = u0 * v0 / (1.f + __expf(-v0));
            float r1 = u1 * v1 / (1.f + __expf(-v1));
            o.u[e >> 1] = pk2(r0, r1);
        }
        *(bfrag*)(R + row * 4096 + ch * 2048 + t8) = o.f;
    }
}

// ---------------------------------------------------------------------------
extern "C" void kernel_launch(void* const* d_in, const int* in_sizes, int n_in,
                              void* d_out, int out_size, void* d_ws, size_t ws_size,
                              hipStream_t stream)
{
    const float* x          = (const float*)d_in[0];
    const float* qkv_w      = (const float*)d_in[1];
    const float* sqk        = (const float*)d_in[2];
    const float* W_O        = (const float*)d_in[3];
    const float* Wu         = (const float*)d_in[4];
    const float* Wv         = (const float*)d_in[5];
    const float* attn_alpha = (const float*)d_in[6];
    const float* mlp_alpha  = (const float*)d_in[7];
    const float* suv        = (const float*)d_in[8];
    float* out = (float*)d_out;

    const long MiB = 1048576;
    char* ws = (char*)d_ws;
    bf16*  x1b   = (bf16*) (ws + 32 * MiB);
    bf16*  QKVb  = (bf16*) (ws + 48 * MiB);
    bf16*  tbufa = (bf16*) (ws + 48 * MiB);   // 16MB, after QKVb dead
    bf16*  tbufb = (bf16*) (ws + 64 * MiB);   // 16MB
    bf16*  uv    = (bf16*) (ws + 48 * MiB);   // half: [4096][8192]
    bf16*  t2a   = (bf16*) (ws + 48 * MiB);   // 16MB, after uv dead
    bf16*  t2b   = (bf16*) (ws + 64 * MiB);   // 16MB
    bf16*  xb    = (bf16*) (ws + 144 * MiB);  // DEAD after step 1 (Qb aliases)
    bf16*  Qb    = (bf16*) (ws + 144 * MiB);
    bf16*  Wub   = (bf16*) (ws + 144 * MiB);
    bf16*  Kb    = (bf16*) (ws + 160 * MiB);
    bf16*  Vt    = (bf16*) (ws + 176 * MiB);
    bf16*  Wvb   = (bf16*) (ws + 176 * MiB);
    bf16*  res   = (bf16*) (ws + 112 * MiB);  // [8192][4096]
    bf16*  qkvwb = (bf16*) (ws + 192 * MiB);
    bf16*  attno = (bf16*) (ws + 192 * MiB);
    bf16*  Wob   = (bf16*) (ws + 208 * MiB);
    // peak 210 MiB

    // 0) converts needed before attn
    f32_to_bf16_k<<<4096, 256, 0, stream>>>(x, xb, 8388608L);
    f32_to_bf16_k<<<1536, 256, 0, stream>>>(qkv_w, qkvwb, 3145728L);
    f32_to_bf16_k<<<512,  256, 0, stream>>>(W_O, Wob, 1048576L);

    // 1) QKV projection -> bf16 [8192][3072]  (256^2 pipelined gemm)
    gemm_bf16_256<bf16><<<dim3(12, 32, 1), 512, 0, stream>>>(
        xb, qkvwb, QKVb, NROW, 3072, DM, DM, 0L);

    // 2) RoPE v2 + justnorm + scaling -> Qb/Kb/Vt (coalesced Vt via LDS)
    rope_norm_qk<<<H_ * B_ * (T_ / 64), 256, 0, stream>>>(QKVb, sqk, Qb, Kb, Vt);

    // 3) MFMA flash attention (8-wave blocks) -> attno bf16
    attn_mfma<<<512, 512, 0, stream>>>(Qb, Kb, Vt, attno);

    // 4) W_O projection, split-K=2 on the 256^2 kernel -> bf16 partials
    //    (QKVb region dead; tbufa/tbufb live there)
    gemm_bf16_256<bf16><<<dim3(4, 32, 2), 512, 0, stream>>>(
        attno, Wob, tbufa, NROW, DM, 512, DM, 8388608L);

    // 5) attention residual lerp-norm -> x1b (t = tbufa + tbufb; A from fp32 x)
    lerp_norm<float, bf16><<<NROW, 256, 0, stream>>>(
        x, tbufa, tbufb, attn_alpha, 1.6f, (float*)nullptr, x1b);

    // 6) weight converts for MLP (Qb/Kb/Vt dead)
    f32_to_bf16_k<<<4096, 256, 0, stream>>>(Wu, Wub, 8388608L);
    f32_to_bf16_k<<<2048, 256, 0, stream>>>(Wv, Wvb, 4194304L);

    // 7) MLP in two M-halves: uv(half) = x1b @ Wu^T -> bf16; act -> res
    for (int half = 0; half < 2; half++) {
        gemm_bf16_256<bf16><<<dim3(32, 16, 1), 512, 0, stream>>>(
            x1b + (long)half * 4096 * DM, Wub, uv, 4096, 8 * DM, DM, DM, 0L);
        mlp_act<<<4096, 256, 0, stream>>>(uv, suv, res + (long)half * 4096 * 4096);
    }
    // note: mlp_act(half2) clobbers Wub region — Wub dead by then.

    // 8) t2 = res @ Wv^T, split-K=2 -> bf16 partials (uv dead; t2a/t2b reuse)
    gemm_bf16_256<bf16><<<dim3(4, 32, 2), 512, 0, stream>>>(
        res, Wvb, t2a, NROW, DM, 2048, 4 * DM, 8388608L);

    // 9) MLP residual lerp-norm -> out (t = t2a + t2b)
    lerp_norm<bf16, bf16><<<NROW, 256, 0, stream>>>(
        x1b, t2a, t2b, mlp_alpha, 0.05f, out, (bf16*)nullptr);
}

// Round 21
// 497.685 us; speedup vs baseline: 1.0001x; 1.0001x over previous
//
#include <hip/hip_runtime.h>
#include <hip/hip_bf16.h>

// nGPT-style transformer layer, MI355X. Round 20: revert round-19's W_O
// split-K experiment (neutral-to-negative; NT=8 too shallow for the 256^2
// pipeline) — restore round-18 verified best (495.7 us): W_O on the 128^2
// kernel, single tbuf, lerp1 without Tt2.
// B=4 T=2048 dm=1024 H=16 di=64.
//
// Workspace arena (peak 210 MiB). Aliasing is ORDER-SENSITIVE; launch order in
// kernel_launch is the contract. xb (144MiB) is DEAD after step 1 (Qb
// aliases). tbuf (48MiB) lives in dead-QKVb region, dead before uv.

#define B_   4
#define T_   2048
#define DM   1024
#define H_   16
#define DI   64
#define NROW (B_ * T_)   // 8192

using bf16 = __hip_bfloat16;
typedef __attribute__((ext_vector_type(8))) short bfrag;   // 8 bf16 (4 VGPR)
typedef __attribute__((ext_vector_type(4))) float f4;

#define EXPB 46.166241f   // 32 * log2(e): sdpa-scale x log2e, folded into Q

__device__ __forceinline__ float ldf(const float* p) { return *p; }
__device__ __forceinline__ float ldf(const bf16* p)  { return __bfloat162float(*p); }
__device__ __forceinline__ void  stf(float* p, float v) { *p = v; }
__device__ __forceinline__ void  stf(bf16* p, float v)  { *p = __float2bfloat16(v); }

__device__ __forceinline__ unsigned short bfbits(float a) {
    bf16 h = __float2bfloat16(a);
    return __builtin_bit_cast(unsigned short, h);
}
__device__ __forceinline__ unsigned pk2(float a, float b) {    // RNE (converts)
    return (unsigned)bfbits(a) | ((unsigned)bfbits(b) << 16);
}
// truncation pack: hi16(a) | hi16(b)<<16 in ONE v_perm_b32 (P in [0,1]).
__device__ __forceinline__ unsigned pk2t(float a, float b) {
    return __builtin_amdgcn_perm(__builtin_bit_cast(unsigned, b),
                                 __builtin_bit_cast(unsigned, a), 0x07060302u);
}

// fast exp2: single v_exp_f32
__device__ __forceinline__ float fexp2(float x) {
    return __builtin_amdgcn_exp2f(x);
}

// vectorized 4-element loads (contiguous per thread)
__device__ __forceinline__ void ld4(const float* p, float* o) {
    float4 v = *(const float4*)p;
    o[0] = v.x; o[1] = v.y; o[2] = v.z; o[3] = v.w;
}
__device__ __forceinline__ void ld4(const bf16* p, float* o) {
    ushort4 v = *(const ushort4*)p;
    o[0] = __builtin_bit_cast(float, (unsigned)v.x << 16);
    o[1] = __builtin_bit_cast(float, (unsigned)v.y << 16);
    o[2] = __builtin_bit_cast(float, (unsigned)v.z << 16);
    o[3] = __builtin_bit_cast(float, (unsigned)v.w << 16);
}

__device__ __forceinline__ float wave_sum(float v) {
#pragma unroll
    for (int off = 32; off; off >>= 1) v += __shfl_xor(v, off, 64);
    return v;
}

__device__ __forceinline__ float block_sum(float v) {
    __shared__ float sm[4];
    int lane = threadIdx.x & 63, w = threadIdx.x >> 6;
    v = wave_sum(v);
    __syncthreads();
    if (lane == 0) sm[w] = v;
    __syncthreads();
    return sm[0] + sm[1] + sm[2] + sm[3];
}

// async global->LDS, 16B per lane; LDS dest = wave-uniform base + lane*16
typedef __attribute__((address_space(1))) const void g_void;
typedef __attribute__((address_space(3))) void l_void;
__device__ __forceinline__ void gl_lds(const void* g, void* l) {
    __builtin_amdgcn_global_load_lds((g_void*)g, (l_void*)l, 16, 0, 0);
}

// ---------------------------------------------------------------------------
// f32 -> bf16 convert, 8 elems/thread. n must be a multiple of 2048.
// ---------------------------------------------------------------------------
__global__ __launch_bounds__(256)
void f32_to_bf16_k(const float* __restrict__ in, bf16* __restrict__ out, long n)
{
    long i = ((long)blockIdx.x * 256 + threadIdx.x) * 8;
    if (i >= n) return;
    float4 a = *(const float4*)(in + i);
    float4 b = *(const float4*)(in + i + 4);
    union { bfrag f; unsigned u[4]; } o;
    o.u[0] = pk2(a.x, a.y); o.u[1] = pk2(a.z, a.w);
    o.u[2] = pk2(b.x, b.y); o.u[3] = pk2(b.z, b.w);
    *(bfrag*)(out + i) = o.f;
}

// ---------------------------------------------------------------------------
// C = A * B^T, 128x128 tile, BK=32, 4 waves, m97 structure (W_O: N=1024).
// ---------------------------------------------------------------------------
template <typename TC>
__global__ __launch_bounds__(256)
void gemm_bf16(const bf16* __restrict__ A, const bf16* __restrict__ Bm,
               TC* __restrict__ C, int M, int N, int K)
{
    __shared__ bf16 lds[2][2][128 * 32];   // [buf][A|B][row*32+k]
    const int tid  = threadIdx.x;
    const int w    = tid >> 6, lane = tid & 63;
    const int g    = lane >> 4, c = lane & 15;
    const int m0   = blockIdx.y * 128, n0 = blockIdx.x * 128;
    const int wm   = w >> 1, wn = w & 1;

    const int srow = (lane >> 2);        // 0..15 within chunk
    const int skc  = 8 * (lane & 3);     // k elem offset 0,8,16,24

    f4 acc[4][4] = {{{0,0,0,0}}};

    const int NT = K >> 5;               // K/32 steps

#pragma unroll
    for (int q = 0; q < 2; q++) {
        int cidx = w * 2 + q;            // 0..7, covers rows [16*cidx,+16)
        int row  = 16 * cidx + srow;
        gl_lds(A + (long)(m0 + row) * K + skc, &lds[0][0][cidx * 512]);
        gl_lds(Bm + (long)(n0 + row) * K + skc, &lds[0][1][cidx * 512]);
    }
    __syncthreads();

    for (int t = 0; t < NT; t++) {
        int cur = t & 1;
        if (t + 1 < NT) {
            int k0 = (t + 1) << 5;
#pragma unroll
            for (int q = 0; q < 2; q++) {
                int cidx = w * 2 + q;
                int row  = 16 * cidx + srow;
                gl_lds(A + (long)(m0 + row) * K + k0 + skc, &lds[cur ^ 1][0][cidx * 512]);
                gl_lds(Bm + (long)(n0 + row) * K + k0 + skc, &lds[cur ^ 1][1][cidx * 512]);
            }
        }
        const bf16* bufA = &lds[cur][0][0];
        const bf16* bufB = &lds[cur][1][0];
        bfrag af[4], bb[4];
#pragma unroll
        for (int mi = 0; mi < 4; mi++)
            af[mi] = *(const bfrag*)(bufA + (64 * wm + 16 * mi + c) * 32 + 8 * g);
#pragma unroll
        for (int ni = 0; ni < 4; ni++)
            bb[ni] = *(const bfrag*)(bufB + (64 * wn + 16 * ni + c) * 32 + 8 * g);
#pragma unroll
        for (int mi = 0; mi < 4; mi++)
#pragma unroll
            for (int ni = 0; ni < 4; ni++)
                acc[mi][ni] = __builtin_amdgcn_mfma_f32_16x16x32_bf16(
                    af[mi], bb[ni], acc[mi][ni], 0, 0, 0);
        __syncthreads();
    }

#pragma unroll
    for (int mi = 0; mi < 4; mi++)
#pragma unroll
        for (int ni = 0; ni < 4; ni++) {
            long row = m0 + 64 * wm + 16 * mi + 4 * g;
            long col = n0 + 64 * wn + 16 * ni + c;
#pragma unroll
            for (int r = 0; r < 4; r++)
                stf(&C[(row + r) * N + col], acc[mi][ni][r]);
        }
}

// ---------------------------------------------------------------------------
// C = A * B^T, 256x256 tile, BK=64, 8 waves (2M x 4N), 128KB LDS dbuf.
// 2-cluster schedule: counted vmcnt(8), (row&7) chunk-XOR swizzle,
// setprio around MFMA clusters. LD = leading dim of A and B (>= K);
// blockIdx.z advances A/B by K elements (split-K) and C by sCz elements.
// M,N %256==0, K %64==0, K>=128.
// ---------------------------------------------------------------------------
template <typename TC>
__global__ __launch_bounds__(512, 2)
void gemm_bf16_256(const bf16* __restrict__ A, const bf16* __restrict__ Bm,
                   TC* __restrict__ C, int M, int N, int K, int LD, long sCz)
{
    A  += (long)blockIdx.z * K;
    Bm += (long)blockIdx.z * K;
    C  += (long)blockIdx.z * sCz;

    __shared__ bf16 lds[2][2][256 * 64];   // 128 KiB
    const int tid  = threadIdx.x;
    const int w    = tid >> 6, lane = tid & 63;
    const int g    = lane >> 4, c = lane & 15;
    const int m0   = blockIdx.y * 256, n0 = blockIdx.x * 256;
    const int wm   = w & 1, wn = w >> 1;          // 2M x 4N wave grid
    const int srow8 = lane >> 3;                  // 0..7
    const int swz   = 8 * ((lane & 7) ^ srow8);   // pre-swizzled source chunk
    const int cx    = c & 7;

    f4 acc[8][4] = {{{0,0,0,0}}};

    const int NT = K >> 6;

    auto STAGE = [&](int buf, int t) {
        int k0 = t << 6;
#pragma unroll
        for (int i = 0; i < 4; i++) {
            int rb = w * 32 + i * 8;              // 8 rows per gl_lds
            gl_lds(A  + (long)(m0 + rb + srow8) * LD + k0 + swz, &lds[buf][0][rb * 64]);
            gl_lds(Bm + (long)(n0 + rb + srow8) * LD + k0 + swz, &lds[buf][1][rb * 64]);
        }
    };

    STAGE(0, 0);
    STAGE(1, 1);
    asm volatile("s_waitcnt vmcnt(8)" ::: "memory");
    __builtin_amdgcn_s_barrier();

    for (int t = 0; t < NT; t++) {
        const bf16* bufA = &lds[t & 1][0][0];
        const bf16* bufB = &lds[t & 1][1][0];

        bfrag a0[4][2], b0[4][2];
#pragma unroll
        for (int mi = 0; mi < 4; mi++)
#pragma unroll
            for (int kk = 0; kk < 2; kk++)
                a0[mi][kk] = *(const bfrag*)(bufA + (wm * 128 + mi * 16 + c) * 64
                                                  + 8 * ((4 * kk + g) ^ cx));
#pragma unroll
        for (int ni = 0; ni < 4; ni++)
#pragma unroll
            for (int kk = 0; kk < 2; kk++)
                b0[ni][kk] = *(const bfrag*)(bufB + (wn * 64 + ni * 16 + c) * 64
                                                  + 8 * ((4 * kk + g) ^ cx));
        asm volatile("s_waitcnt lgkmcnt(0)" ::: "memory");
        __builtin_amdgcn_sched_barrier(0);
        __builtin_amdgcn_s_setprio(1);
#pragma unroll
        for (int mi = 0; mi < 4; mi++)
#pragma unroll
            for (int ni = 0; ni < 4; ni++) {
                acc[mi][ni] = __builtin_amdgcn_mfma_f32_16x16x32_bf16(
                    a0[mi][0], b0[ni][0], acc[mi][ni], 0, 0, 0);
                acc[mi][ni] = __builtin_amdgcn_mfma_f32_16x16x32_bf16(
                    a0[mi][1], b0[ni][1], acc[mi][ni], 0, 0, 0);
            }
        __builtin_amdgcn_s_setprio(0);

        bfrag a1[4][2];
#pragma unroll
        for (int mi = 0; mi < 4; mi++)
#pragma unroll
            for (int kk = 0; kk < 2; kk++)
                a1[mi][kk] = *(const bfrag*)(bufA + (wm * 128 + (mi + 4) * 16 + c) * 64
                                                  + 8 * ((4 * kk + g) ^ cx));
        asm volatile("s_waitcnt lgkmcnt(0)" ::: "memory");
        __builtin_amdgcn_sched_barrier(0);
        __builtin_amdgcn_s_setprio(1);
#pragma unroll
        for (int mi = 0; mi < 4; mi++)
#pragma unroll
            for (int ni = 0; ni < 4; ni++) {
                acc[mi + 4][ni] = __builtin_amdgcn_mfma_f32_16x16x32_bf16(
                    a1[mi][0], b0[ni][0], acc[mi + 4][ni], 0, 0, 0);
                acc[mi + 4][ni] = __builtin_amdgcn_mfma_f32_16x16x32_bf16(
                    a1[mi][1], b0[ni][1], acc[mi + 4][ni], 0, 0, 0);
            }
        __builtin_amdgcn_s_setprio(0);

        __builtin_amdgcn_s_barrier();
        if (t + 2 < NT) {
            STAGE(t & 1, t + 2);
            asm volatile("s_waitcnt vmcnt(8)" ::: "memory");
        } else if (t + 1 < NT) {
            asm volatile("s_waitcnt vmcnt(0)" ::: "memory");
        }
        __builtin_amdgcn_s_barrier();
    }

#pragma unroll
    for (int mi = 0; mi < 8; mi++)
#pragma unroll
        for (int ni = 0; ni < 4; ni++) {
            long row = m0 + wm * 128 + mi * 16 + 4 * g;
            long col = n0 + wn * 64 + ni * 16 + c;
#pragma unroll
            for (int r = 0; r < 4; r++)
                stf(&C[(row + r) * N + col], acc[mi][ni][r]);
        }
}

// ---------------------------------------------------------------------------
// RoPE v2 + per-row L2 norm + sqk*sqrt(dm); QKVb bf16 layout [row][h*192+e].
// Block = (h, b, 64-wide t-tile); 4 waves x 16 rows. V staged in LDS [64][66]
// then written as 16 contiguous t-elems per thread -> coalesced Vt.
// Qb carries sdpa sqrt(dm)=32 AND log2e (exp2 path in attn).
// ---------------------------------------------------------------------------
__global__ __launch_bounds__(256)
void rope_norm_qk(const bf16* __restrict__ QKVb, const float* __restrict__ sqk,
                  bf16* __restrict__ Qb, bf16* __restrict__ Kb, bf16* __restrict__ Vt)
{
    __shared__ unsigned short vbuf[64][66];   // pad 66 -> <=4-way on gather

    int bid  = blockIdx.x;                // 0..2047
    int h    = bid >> 7;                  // / (B_*32)
    int rem  = bid & 127;
    int b    = rem >> 5;
    int tile = rem & 31;
    int w    = threadIdx.x >> 6;
    int lane = threadIdx.x & 63;

    int   j       = lane & 31;
    // inv_rev = 10000^(-j/32) / (2*pi);  log2(10000)/32 = 0.41524101
    float inv_rev = fexp2(-(float)j * 0.41524101f) * 0.15915494f;
    float se      = sqk[h * 64 + lane] * 32.f;   // sqk * sqrt(dm)

#pragma unroll 1
    for (int i = 0; i < 16; i++) {
        int tl = i * 4 + w;               // 0..63
        int t  = tile * 64 + tl;
        long row = (long)b * T_ + t;
        const bf16* base = QKVb + row * 3072 + h * 192;
        float q = ldf(base + lane);
        float k = ldf(base + 64 + lane);
        unsigned short vb = ((const unsigned short*)base)[128 + lane];

        float ar = (float)t * inv_rev;
        ar = ar - floorf(ar);                       // revolutions in [0,1)
        float s  = __builtin_amdgcn_sinf(ar);
        float cc = __builtin_amdgcn_cosf(ar);

        float qp = __shfl_xor(q, 32, 64);
        float kp = __shfl_xor(k, 32, 64);
        float sgn = (lane < 32) ? -1.f : 1.f;
        float qr = q * cc + sgn * qp * s;
        float kr = k * cc + sgn * kp * s;

        float qs = wave_sum(qr * qr);
        float ks = wave_sum(kr * kr);

        long idx = ((long)h * NROW + row) * 64 + lane;
        Qb[idx] = __float2bfloat16(qr * rsqrtf(qs) * se * EXPB);  // 32*log2e
        Kb[idx] = __float2bfloat16(kr * rsqrtf(ks) * se);
        vbuf[tl][lane] = vb;
    }
    __syncthreads();

    // V transpose write: thread -> (d = tid>>2, 16 t's at seg*16)
    int d   = threadIdx.x >> 2;
    int seg = threadIdx.x & 3;
    union { bfrag f; unsigned short s[8]; } o0, o1;
#pragma unroll
    for (int jj = 0; jj < 8; jj++) {
        o0.s[jj] = vbuf[seg * 16 + jj][d];
        o1.s[jj] = vbuf[seg * 16 + 8 + jj][d];
    }
    bf16* dst = Vt + ((long)(h * B_ + b) * 64 + d) * T_ + tile * 64 + seg * 16;
    *(bfrag*)dst       = o0.f;
    *(bfrag*)(dst + 8) = o1.f;
}

// ---------------------------------------------------------------------------
// MFMA flash attention, exp2 fixed-shift softmax (C-init = -EXPB), paired
// q-tiles. 8-wave blocks (512 thr), K/V LDS staging shared by 8 waves.
// Per-wave ranges differ by <=1 iteration (nA = 2*blk + (w>=4)); actA/actB
// guards wave-uniform. Heavy/light blk interleave; XCD swizzle.
// ---------------------------------------------------------------------------
__global__ __launch_bounds__(512)
void attn_mfma(const bf16* __restrict__ Qb, const bf16* __restrict__ Kb,
               const bf16* __restrict__ Vt, bf16* __restrict__ O)
{
    __shared__ bf16 kv[2][2][64 * 64];    // [buf][K|V][row*64 + chunk-swizzled]

    int orig   = blockIdx.x;              // 0..511
    int xcd    = orig & 7;
    int rest   = orig >> 3;               // 0..63
    int bh     = xcd * 8 + (rest & 7);    // 8 (b,h) per XCD -> 4MiB K/V in L2
    int blkraw = rest >> 3;               // 0..7
    int blk    = (blkraw & 1) ? (7 - (blkraw >> 1)) : (blkraw >> 1);
    int w      = threadIdx.x >> 6;        // 0..7
    int pr     = blk * 8 + w;             // 0..63
    int h = bh >> 2, b = bh & 3;

    int lane = threadIdx.x & 63;
    int g = lane >> 4, c = lane & 15;

    const bf16* kbase = Kb + ((long)h * NROW + (long)b * T_) * 64;
    const bf16* vbase = Vt + (long)(h * B_ + b) * 64 * (long)T_;

    int q0A = pr * 16, q0B = (127 - pr) * 16;
    const bf16* qbA = Qb + ((long)h * NROW + (long)b * T_ + q0A) * 64;
    const bf16* qbB = Qb + ((long)h * NROW + (long)b * T_ + q0B) * 64;
    bfrag qfA0 = *(const bfrag*)(qbA + (long)c * 64 + 8 * g);
    bfrag qfA1 = *(const bfrag*)(qbA + (long)c * 64 + 32 + 8 * g);
    bfrag qfB0 = *(const bfrag*)(qbB + (long)c * 64 + 8 * g);
    bfrag qfB1 = *(const bfrag*)(qbB + (long)c * 64 + 32 + 8 * g);

    const f4 CINIT = {-EXPB, -EXPB, -EXPB, -EXPB};

    f4 otA[4] = {{0,0,0,0},{0,0,0,0},{0,0,0,0},{0,0,0,0}};
    f4 otB[4] = {{0,0,0,0},{0,0,0,0},{0,0,0,0},{0,0,0,0}};
    float lA = 0.f, lB = 0.f;

    const int nA = pr >> 2;               // 2*blk + (w>=4)
    const int nB = 31 - nA;
    const int KTblk = 31 - 2 * blk;       // block-uniform loop bound (max nB)
    int qgA = q0A + c, qgB = q0B + c;

    const int srow8  = lane >> 3;                 // 0..7
    const int swz    = 8 * ((lane & 7) ^ srow8);  // swizzled source chunk

    auto STAGE = [&](int buf, int kt) {
        int k0 = kt * 64;
        int row = w * 8 + srow8;                  // 8 waves cover 64 rows
        gl_lds(kbase + (long)(k0 + row) * 64 + swz, &kv[buf][0][w * 8 * 64]);
        gl_lds(vbase + (long)row * T_ + k0 + swz,   &kv[buf][1][w * 8 * 64]);
    };

    STAGE(0, 0);
    __syncthreads();

    const int cx = c & 7;

    for (int kt = 0; kt <= KTblk; kt++) {
        int buf = kt & 1;
        if (kt < KTblk) STAGE(buf ^ 1, kt + 1);

        const bf16* Kl = &kv[buf][0][0];
        const bf16* Vl = &kv[buf][1][0];
        int k0 = kt * 64;
        bool actA = (kt <= nA);           // wave-uniform
        bool actB = (kt <= nB);           // wave-uniform
        unsigned wvA[8], wvB[8];

        if (actA || actB) {
#pragma unroll
            for (int kb = 0; kb < 4; kb++) {
                const bf16* kr = Kl + (16 * kb + c) * 64;
                bfrag ka = *(const bfrag*)(kr + 8 * (g ^ cx));
                bfrag kc = *(const bfrag*)(kr + 8 * ((g | 4) ^ cx));

                if (actB) {
                    f4 sB = __builtin_amdgcn_mfma_f32_16x16x32_bf16(ka, qfB0, CINIT, 0, 0, 0);
                    sB = __builtin_amdgcn_mfma_f32_16x16x32_bf16(kc, qfB1, sB, 0, 0, 0);
                    if (kt == nB) {
#pragma unroll
                        for (int r = 0; r < 4; r++)
                            if (k0 + 16 * kb + 4 * g + r > qgB) sB[r] = -1e30f;
                    }
                    float eB0 = fexp2(sB[0]), eB1 = fexp2(sB[1]);
                    float eB2 = fexp2(sB[2]), eB3 = fexp2(sB[3]);
                    lB += (eB0 + eB1) + (eB2 + eB3);
                    wvB[2 * kb]     = pk2t(eB0, eB1);
                    wvB[2 * kb + 1] = pk2t(eB2, eB3);
                }

                if (actA) {
                    f4 sA = __builtin_amdgcn_mfma_f32_16x16x32_bf16(ka, qfA0, CINIT, 0, 0, 0);
                    sA = __builtin_amdgcn_mfma_f32_16x16x32_bf16(kc, qfA1, sA, 0, 0, 0);
                    if (kt == nA) {
#pragma unroll
                        for (int r = 0; r < 4; r++)
                            if (k0 + 16 * kb + 4 * g + r > qgA) sA[r] = -1e30f;
                    }
                    float eA0 = fexp2(sA[0]), eA1 = fexp2(sA[1]);
                    float eA2 = fexp2(sA[2]), eA3 = fexp2(sA[3]);
                    lA += (eA0 + eA1) + (eA2 + eA3);
                    wvA[2 * kb]     = pk2t(eA0, eA1);
                    wvA[2 * kb + 1] = pk2t(eA2, eA3);
                }
            }

            // PV: two 32-key halves; B-frag = P^T via lane exchange; V from LDS
#pragma unroll
            for (int p = 0; p < 2; p++) {
                int s0l = c + 32 * (g & 1), s1l = s0l + 16;
                bool hi = (g >= 2);

                union { bfrag f; unsigned u[4]; } pfB, pfA;
                if (actB) {
                    unsigned Bb0 = (unsigned)__shfl((int)wvB[4 * p + 0], s0l, 64);
                    unsigned Bb1 = (unsigned)__shfl((int)wvB[4 * p + 1], s0l, 64);
                    unsigned Bb2 = (unsigned)__shfl((int)wvB[4 * p + 2], s0l, 64);
                    unsigned Bb3 = (unsigned)__shfl((int)wvB[4 * p + 3], s0l, 64);
                    unsigned Bb4 = (unsigned)__shfl((int)wvB[4 * p + 0], s1l, 64);
                    unsigned Bb5 = (unsigned)__shfl((int)wvB[4 * p + 1], s1l, 64);
                    unsigned Bb6 = (unsigned)__shfl((int)wvB[4 * p + 2], s1l, 64);
                    unsigned Bb7 = (unsigned)__shfl((int)wvB[4 * p + 3], s1l, 64);
                    pfB.u[0] = hi ? Bb2 : Bb0;
                    pfB.u[1] = hi ? Bb3 : Bb1;
                    pfB.u[2] = hi ? Bb6 : Bb4;
                    pfB.u[3] = hi ? Bb7 : Bb5;
                }
                if (actA) {
                    unsigned Ab0 = (unsigned)__shfl((int)wvA[4 * p + 0], s0l, 64);
                    unsigned Ab1 = (unsigned)__shfl((int)wvA[4 * p + 1], s0l, 64);
                    unsigned Ab2 = (unsigned)__shfl((int)wvA[4 * p + 2], s0l, 64);
                    unsigned Ab3 = (unsigned)__shfl((int)wvA[4 * p + 3], s0l, 64);
                    unsigned Ab4 = (unsigned)__shfl((int)wvA[4 * p + 0], s1l, 64);
                    unsigned Ab5 = (unsigned)__shfl((int)wvA[4 * p + 1], s1l, 64);
                    unsigned Ab6 = (unsigned)__shfl((int)wvA[4 * p + 2], s1l, 64);
                    unsigned Ab7 = (unsigned)__shfl((int)wvA[4 * p + 3], s1l, 64);
                    pfA.u[0] = hi ? Ab2 : Ab0;
                    pfA.u[1] = hi ? Ab3 : Ab1;
                    pfA.u[2] = hi ? Ab6 : Ab4;
                    pfA.u[3] = hi ? Ab7 : Ab5;
                }

#pragma unroll
                for (int dblk = 0; dblk < 4; dblk++) {
                    bfrag vf = *(const bfrag*)(Vl + (16 * dblk + c) * 64
                                                  + 8 * (((p << 2) | g) ^ cx));
                    if (actB)
                        otB[dblk] = __builtin_amdgcn_mfma_f32_16x16x32_bf16(vf, pfB.f, otB[dblk], 0, 0, 0);
                    if (actA)
                        otA[dblk] = __builtin_amdgcn_mfma_f32_16x16x32_bf16(vf, pfA.f, otA[dblk], 0, 0, 0);
                }
            }
        }
        __syncthreads();
    }

    lA += __shfl_xor(lA, 16, 64); lA += __shfl_xor(lA, 32, 64);
    lB += __shfl_xor(lB, 16, 64); lB += __shfl_xor(lB, 32, 64);

    float invA = 1.f / lA, invB = 1.f / lB;
    long orowA = (long)(b * T_ + q0A + c) * DM + h * 64;
    long orowB = (long)(b * T_ + q0B + c) * DM + h * 64;
#pragma unroll
    for (int dblk = 0; dblk < 4; dblk++)
#pragma unroll
        for (int r = 0; r < 4; r++) {
            O[orowA + 16 * dblk + 4 * g + r] = __float2bfloat16(otA[dblk][r] * invA);
            O[orowB + 16 * dblk + 4 * g + r] = __float2bfloat16(otB[dblk][r] * invB);
        }
}

// ---------------------------------------------------------------------------
// Out = justnorm(A + lr*(Bn - A)); t-input = Tt (+ Tt2 if non-null, summed).
// Vectorized: thread handles 4 contiguous elems at tid*4.
// ---------------------------------------------------------------------------
template <typename TX, typename TT>
__global__ __launch_bounds__(256)
void lerp_norm(const TX* __restrict__ X, const TT* __restrict__ Tt,
               const TT* __restrict__ Tt2, const float* __restrict__ alpha,
               float ascale, float* __restrict__ OutF, bf16* __restrict__ OutB)
{
    long row = blockIdx.x;
    int t4 = threadIdx.x * 4;
    const TX* xr = X  + row * DM + t4;
    const TT* tr = Tt + row * DM + t4;

    float xs[4], ts[4];
    ld4(xr, xs);
    ld4(tr, ts);
    if (Tt2) {
        float t2[4];
        ld4(Tt2 + row * DM + t4, t2);
#pragma unroll
        for (int i = 0; i < 4; i++) ts[i] += t2[i];
    }
    float sx = 0.f, st = 0.f;
#pragma unroll
    for (int i = 0; i < 4; i++) { sx += xs[i] * xs[i]; st += ts[i] * ts[i]; }
    sx = block_sum(sx);
    st = block_sum(st);
    float ix = rsqrtf(sx), it = rsqrtf(st);

    float4 al = *(const float4*)(alpha + t4);
    float av[4] = {al.x, al.y, al.z, al.w};
    float ys[4], sy = 0.f;
#pragma unroll
    for (int i = 0; i < 4; i++) {
        float a  = xs[i] * ix;
        float bn = ts[i] * it;
        float lr = fabsf(av[i] * ascale);
        ys[i] = a + lr * (bn - a);
        sy += ys[i] * ys[i];
    }
    sy = block_sum(sy);
    float iy = rsqrtf(sy);
#pragma unroll
    for (int i = 0; i < 4; i++) ys[i] *= iy;

    if (OutF) *(float4*)(OutF + row * DM + t4) = make_float4(ys[0], ys[1], ys[2], ys[3]);
    if (OutB) {
        uint2 o;
        o.x = pk2(ys[0], ys[1]);
        o.y = pk2(ys[2], ys[3]);
        *(uint2*)(OutB + row * DM + t4) = o;
    }
}

// ---------------------------------------------------------------------------
// tn = justnorm(suv*32*uv_row[8192]); res = u*silu(v). Vectorized single-pass.
// ---------------------------------------------------------------------------
__global__ __launch_bounds__(256)
void mlp_act(const bf16* __restrict__ UV, const float* __restrict__ suv,
             bf16* __restrict__ R)
{
    long row = blockIdx.x;
    const bf16* ur = UV + row * 8192;
    int t8 = threadIdx.x * 8;

    float f[4][8];
    float ss = 0.f;
#pragma unroll
    for (int ch = 0; ch < 4; ch++) {
        bfrag d = *(const bfrag*)(ur + ch * 2048 + t8);
        const float4* sp = (const float4*)(suv + ch * 2048 + t8);
        float4 s0 = sp[0], s1 = sp[1];
        float sv[8] = {s0.x, s0.y, s0.z, s0.w, s1.x, s1.y, s1.z, s1.w};
#pragma unroll
        for (int e = 0; e < 8; e++) {
            unsigned short us = __builtin_bit_cast(unsigned short, (short)d[e]);
            float v = __builtin_bit_cast(float, (unsigned)us << 16) * sv[e] * 32.f;
            f[ch][e] = v;
            ss += v * v;
        }
    }
    ss = block_sum(ss);
    float inv = rsqrtf(ss);

#pragma unroll
    for (int ch = 0; ch < 2; ch++) {
        union { bfrag f; unsigned u[4]; } o;
#pragma unroll
        for (int e = 0; e < 8; e += 2) {
            float u0 = f[ch][e]     * inv, u1 = f[ch][e + 1]     * inv;
            float v0 = f[ch + 2][e] * inv, v1 = f[ch + 2][e + 1] * inv;
            float r0 = u0 * v0 / (1.f + __expf(-v0));
            float r1 = u1 * v1 / (1.f + __expf(-v1));
            o.u[e >> 1] = pk2(r0, r1);
        }
        *(bfrag*)(R + row * 4096 + ch * 2048 + t8) = o.f;
    }
}

// ---------------------------------------------------------------------------
extern "C" void kernel_launch(void* const* d_in, const int* in_sizes, int n_in,
                              void* d_out, int out_size, void* d_ws, size_t ws_size,
                              hipStream_t stream)
{
    const float* x          = (const float*)d_in[0];
    const float* qkv_w      = (const float*)d_in[1];
    const float* sqk        = (const float*)d_in[2];
    const float* W_O        = (const float*)d_in[3];
    const float* Wu         = (const float*)d_in[4];
    const float* Wv         = (const float*)d_in[5];
    const float* attn_alpha = (const float*)d_in[6];
    const float* mlp_alpha  = (const float*)d_in[7];
    const float* suv        = (const float*)d_in[8];
    float* out = (float*)d_out;

    const long MiB = 1048576;
    char* ws = (char*)d_ws;
    bf16*  x1b   = (bf16*) (ws + 32 * MiB);
    bf16*  QKVb  = (bf16*) (ws + 48 * MiB);
    bf16*  tbuf  = (bf16*) (ws + 48 * MiB);   // 16MB, after QKVb dead
    bf16*  uv    = (bf16*) (ws + 48 * MiB);   // half: [4096][8192]
    bf16*  t2a   = (bf16*) (ws + 48 * MiB);   // 16MB, after uv dead
    bf16*  t2b   = (bf16*) (ws + 64 * MiB);   // 16MB
    bf16*  xb    = (bf16*) (ws + 144 * MiB);  // DEAD after step 1 (Qb aliases)
    bf16*  Qb    = (bf16*) (ws + 144 * MiB);
    bf16*  Wub   = (bf16*) (ws + 144 * MiB);
    bf16*  Kb    = (bf16*) (ws + 160 * MiB);
    bf16*  Vt    = (bf16*) (ws + 176 * MiB);
    bf16*  Wvb   = (bf16*) (ws + 176 * MiB);
    bf16*  res   = (bf16*) (ws + 112 * MiB);  // [8192][4096]
    bf16*  qkvwb = (bf16*) (ws + 192 * MiB);
    bf16*  attno = (bf16*) (ws + 192 * MiB);
    bf16*  Wob   = (bf16*) (ws + 208 * MiB);
    // peak 210 MiB

    // 0) converts needed before attn
    f32_to_bf16_k<<<4096, 256, 0, stream>>>(x, xb, 8388608L);
    f32_to_bf16_k<<<1536, 256, 0, stream>>>(qkv_w, qkvwb, 3145728L);
    f32_to_bf16_k<<<512,  256, 0, stream>>>(W_O, Wob, 1048576L);

    // 1) QKV projection -> bf16 [8192][3072]  (256^2 pipelined gemm)
    gemm_bf16_256<bf16><<<dim3(12, 32, 1), 512, 0, stream>>>(
        xb, qkvwb, QKVb, NROW, 3072, DM, DM, 0L);

    // 2) RoPE v2 + justnorm + scaling -> Qb/Kb/Vt (coalesced Vt via LDS)
    rope_norm_qk<<<H_ * B_ * (T_ / 64), 256, 0, stream>>>(QKVb, sqk, Qb, Kb, Vt);

    // 3) MFMA flash attention (8-wave blocks) -> attno bf16
    attn_mfma<<<512, 512, 0, stream>>>(Qb, Kb, Vt, attno);

    // 4) W_O projection -> tbuf bf16 (128^2 kernel; QKVb region dead)
    gemm_bf16<bf16><<<dim3(8, 64), 256, 0, stream>>>(attno, Wob, tbuf, NROW, DM, DM);

    // 5) attention residual lerp-norm -> x1b (A from pristine fp32 x;
    //    xb is DEAD here — Qb overwrote it in step 2)
    lerp_norm<float, bf16><<<NROW, 256, 0, stream>>>(
        x, tbuf, (const bf16*)nullptr, attn_alpha, 1.6f, (float*)nullptr, x1b);

    // 6) weight converts for MLP (Qb/Kb/Vt dead)
    f32_to_bf16_k<<<4096, 256, 0, stream>>>(Wu, Wub, 8388608L);
    f32_to_bf16_k<<<2048, 256, 0, stream>>>(Wv, Wvb, 4194304L);

    // 7) MLP in two M-halves: uv(half) = x1b @ Wu^T -> bf16; act -> res
    for (int half = 0; half < 2; half++) {
        gemm_bf16_256<bf16><<<dim3(32, 16, 1), 512, 0, stream>>>(
            x1b + (long)half * 4096 * DM, Wub, uv, 4096, 8 * DM, DM, DM, 0L);
        mlp_act<<<4096, 256, 0, stream>>>(uv, suv, res + (long)half * 4096 * 4096);
    }
    // note: mlp_act(half2) clobbers Wub region — Wub dead by then.

    // 8) t2 = res @ Wv^T, split-K=2 -> bf16 partials (uv dead; t2a/t2b reuse)
    gemm_bf16_256<bf16><<<dim3(4, 32, 2), 512, 0, stream>>>(
        res, Wvb, t2a, NROW, DM, 2048, 4 * DM, 8388608L);

    // 9) MLP residual lerp-norm -> out (t = t2a + t2b)
    lerp_norm<bf16, bf16><<<NROW, 256, 0, stream>>>(
        x1b, t2a, t2b, mlp_alpha, 0.05f, out, (bf16*)nullptr);
}

// Round 22
// 491.305 us; speedup vs baseline: 1.0131x; 1.0130x over previous
//
#include <hip/hip_runtime.h>
#include <hip/hip_bf16.h>

// nGPT-style transformer layer, MI355X. Round 21: fuse all 5 f32->bf16
// converts into ONE segmented kernel at step 0 (13 -> 9 dispatches).
// Wub moved to ws+0, Wvb to ws+16MiB (region free since round 10) so the
// weight converts no longer alias rope outputs. Rest = round-20 best-known.
// B=4 T=2048 dm=1024 H=16 di=64.
//
// Workspace arena (peak 210 MiB). Aliasing is ORDER-SENSITIVE; launch order in
// kernel_launch is the contract.
//   [0,  16M)  Wub  bf16 [8192][1024]   (convert step 0 -> Wu gemm)
//   [16, 24M)  Wvb  bf16 [1024][4096]   (convert step 0 -> Wv gemm)
//   [32, 48M)  x1b; [48,96M) QKVb; [48,64M) tbuf/t2a (after QKVb/uv dead);
//   [64,80M) t2b; [48,112M) uv halves; [112,176M) res; [144,160M) xb/Qb;
//   [160,176M) Kb; [176,192M) Vt; [192,208M) qkvwb/attno; [208,210M) Wob.

#define B_   4
#define T_   2048
#define DM   1024
#define H_   16
#define DI   64
#define NROW (B_ * T_)   // 8192

using bf16 = __hip_bfloat16;
typedef __attribute__((ext_vector_type(8))) short bfrag;   // 8 bf16 (4 VGPR)
typedef __attribute__((ext_vector_type(4))) float f4;

#define EXPB 46.166241f   // 32 * log2(e): sdpa-scale x log2e, folded into Q

__device__ __forceinline__ float ldf(const float* p) { return *p; }
__device__ __forceinline__ float ldf(const bf16* p)  { return __bfloat162float(*p); }
__device__ __forceinline__ void  stf(float* p, float v) { *p = v; }
__device__ __forceinline__ void  stf(bf16* p, float v)  { *p = __float2bfloat16(v); }

__device__ __forceinline__ unsigned short bfbits(float a) {
    bf16 h = __float2bfloat16(a);
    return __builtin_bit_cast(unsigned short, h);
}
__device__ __forceinline__ unsigned pk2(float a, float b) {    // RNE (converts)
    return (unsigned)bfbits(a) | ((unsigned)bfbits(b) << 16);
}
// truncation pack: hi16(a) | hi16(b)<<16 in ONE v_perm_b32 (P in [0,1]).
__device__ __forceinline__ unsigned pk2t(float a, float b) {
    return __builtin_amdgcn_perm(__builtin_bit_cast(unsigned, b),
                                 __builtin_bit_cast(unsigned, a), 0x07060302u);
}

// fast exp2: single v_exp_f32
__device__ __forceinline__ float fexp2(float x) {
    return __builtin_amdgcn_exp2f(x);
}

// vectorized 4-element loads (contiguous per thread)
__device__ __forceinline__ void ld4(const float* p, float* o) {
    float4 v = *(const float4*)p;
    o[0] = v.x; o[1] = v.y; o[2] = v.z; o[3] = v.w;
}
__device__ __forceinline__ void ld4(const bf16* p, float* o) {
    ushort4 v = *(const ushort4*)p;
    o[0] = __builtin_bit_cast(float, (unsigned)v.x << 16);
    o[1] = __builtin_bit_cast(float, (unsigned)v.y << 16);
    o[2] = __builtin_bit_cast(float, (unsigned)v.z << 16);
    o[3] = __builtin_bit_cast(float, (unsigned)v.w << 16);
}

__device__ __forceinline__ float wave_sum(float v) {
#pragma unroll
    for (int off = 32; off; off >>= 1) v += __shfl_xor(v, off, 64);
    return v;
}

__device__ __forceinline__ float block_sum(float v) {
    __shared__ float sm[4];
    int lane = threadIdx.x & 63, w = threadIdx.x >> 6;
    v = wave_sum(v);
    __syncthreads();
    if (lane == 0) sm[w] = v;
    __syncthreads();
    return sm[0] + sm[1] + sm[2] + sm[3];
}

// async global->LDS, 16B per lane; LDS dest = wave-uniform base + lane*16
typedef __attribute__((address_space(1))) const void g_void;
typedef __attribute__((address_space(3))) void l_void;
__device__ __forceinline__ void gl_lds(const void* g, void* l) {
    __builtin_amdgcn_global_load_lds((g_void*)g, (l_void*)l, 16, 0, 0);
}

// ---------------------------------------------------------------------------
// Fused f32 -> bf16 converts: 5 segments, one launch. Each block converts
// 2048 contiguous elements of its segment (8 per thread). Segment block
// counts: x 4096 | qkv_w 1536 | W_O 512 | Wu 4096 | Wv 2048  (total 12288).
// ---------------------------------------------------------------------------
__global__ __launch_bounds__(256)
void convert_all_k(const float* __restrict__ x,    bf16* __restrict__ xb,
                   const float* __restrict__ qkvw, bf16* __restrict__ qkvwb,
                   const float* __restrict__ wo,   bf16* __restrict__ wob,
                   const float* __restrict__ wu,   bf16* __restrict__ wub,
                   const float* __restrict__ wv,   bf16* __restrict__ wvb)
{
    int bid = blockIdx.x;
    const float* src; bf16* dst; long base;
    if (bid < 4096)       { src = x;    dst = xb;    base = (long)bid * 2048; }
    else if (bid < 5632)  { src = qkvw; dst = qkvwb; base = (long)(bid - 4096) * 2048; }
    else if (bid < 6144)  { src = wo;   dst = wob;   base = (long)(bid - 5632) * 2048; }
    else if (bid < 10240) { src = wu;   dst = wub;   base = (long)(bid - 6144) * 2048; }
    else                  { src = wv;   dst = wvb;   base = (long)(bid - 10240) * 2048; }

    long i = base + (long)threadIdx.x * 8;
    float4 a = *(const float4*)(src + i);
    float4 b = *(const float4*)(src + i + 4);
    union { bfrag f; unsigned u[4]; } o;
    o.u[0] = pk2(a.x, a.y); o.u[1] = pk2(a.z, a.w);
    o.u[2] = pk2(b.x, b.y); o.u[3] = pk2(b.z, b.w);
    *(bfrag*)(dst + i) = o.f;
}

// ---------------------------------------------------------------------------
// C = A * B^T, 128x128 tile, BK=32, 4 waves, m97 structure (W_O: N=1024).
// ---------------------------------------------------------------------------
template <typename TC>
__global__ __launch_bounds__(256)
void gemm_bf16(const bf16* __restrict__ A, const bf16* __restrict__ Bm,
               TC* __restrict__ C, int M, int N, int K)
{
    __shared__ bf16 lds[2][2][128 * 32];   // [buf][A|B][row*32+k]
    const int tid  = threadIdx.x;
    const int w    = tid >> 6, lane = tid & 63;
    const int g    = lane >> 4, c = lane & 15;
    const int m0   = blockIdx.y * 128, n0 = blockIdx.x * 128;
    const int wm   = w >> 1, wn = w & 1;

    const int srow = (lane >> 2);        // 0..15 within chunk
    const int skc  = 8 * (lane & 3);     // k elem offset 0,8,16,24

    f4 acc[4][4] = {{{0,0,0,0}}};

    const int NT = K >> 5;               // K/32 steps

#pragma unroll
    for (int q = 0; q < 2; q++) {
        int cidx = w * 2 + q;            // 0..7, covers rows [16*cidx,+16)
        int row  = 16 * cidx + srow;
        gl_lds(A + (long)(m0 + row) * K + skc, &lds[0][0][cidx * 512]);
        gl_lds(Bm + (long)(n0 + row) * K + skc, &lds[0][1][cidx * 512]);
    }
    __syncthreads();

    for (int t = 0; t < NT; t++) {
        int cur = t & 1;
        if (t + 1 < NT) {
            int k0 = (t + 1) << 5;
#pragma unroll
            for (int q = 0; q < 2; q++) {
                int cidx = w * 2 + q;
                int row  = 16 * cidx + srow;
                gl_lds(A + (long)(m0 + row) * K + k0 + skc, &lds[cur ^ 1][0][cidx * 512]);
                gl_lds(Bm + (long)(n0 + row) * K + k0 + skc, &lds[cur ^ 1][1][cidx * 512]);
            }
        }
        const bf16* bufA = &lds[cur][0][0];
        const bf16* bufB = &lds[cur][1][0];
        bfrag af[4], bb[4];
#pragma unroll
        for (int mi = 0; mi < 4; mi++)
            af[mi] = *(const bfrag*)(bufA + (64 * wm + 16 * mi + c) * 32 + 8 * g);
#pragma unroll
        for (int ni = 0; ni < 4; ni++)
            bb[ni] = *(const bfrag*)(bufB + (64 * wn + 16 * ni + c) * 32 + 8 * g);
#pragma unroll
        for (int mi = 0; mi < 4; mi++)
#pragma unroll
            for (int ni = 0; ni < 4; ni++)
                acc[mi][ni] = __builtin_amdgcn_mfma_f32_16x16x32_bf16(
                    af[mi], bb[ni], acc[mi][ni], 0, 0, 0);
        __syncthreads();
    }

#pragma unroll
    for (int mi = 0; mi < 4; mi++)
#pragma unroll
        for (int ni = 0; ni < 4; ni++) {
            long row = m0 + 64 * wm + 16 * mi + 4 * g;
            long col = n0 + 64 * wn + 16 * ni + c;
#pragma unroll
            for (int r = 0; r < 4; r++)
                stf(&C[(row + r) * N + col], acc[mi][ni][r]);
        }
}

// ---------------------------------------------------------------------------
// C = A * B^T, 256x256 tile, BK=64, 8 waves (2M x 4N), 128KB LDS dbuf.
// 2-cluster schedule: counted vmcnt(8), (row&7) chunk-XOR swizzle,
// setprio around MFMA clusters. LD = leading dim of A and B (>= K);
// blockIdx.z advances A/B by K elements (split-K) and C by sCz elements.
// M,N %256==0, K %64==0, K>=128.
// ---------------------------------------------------------------------------
template <typename TC>
__global__ __launch_bounds__(512, 2)
void gemm_bf16_256(const bf16* __restrict__ A, const bf16* __restrict__ Bm,
                   TC* __restrict__ C, int M, int N, int K, int LD, long sCz)
{
    A  += (long)blockIdx.z * K;
    Bm += (long)blockIdx.z * K;
    C  += (long)blockIdx.z * sCz;

    __shared__ bf16 lds[2][2][256 * 64];   // 128 KiB
    const int tid  = threadIdx.x;
    const int w    = tid >> 6, lane = tid & 63;
    const int g    = lane >> 4, c = lane & 15;
    const int m0   = blockIdx.y * 256, n0 = blockIdx.x * 256;
    const int wm   = w & 1, wn = w >> 1;          // 2M x 4N wave grid
    const int srow8 = lane >> 3;                  // 0..7
    const int swz   = 8 * ((lane & 7) ^ srow8);   // pre-swizzled source chunk
    const int cx    = c & 7;

    f4 acc[8][4] = {{{0,0,0,0}}};

    const int NT = K >> 6;

    auto STAGE = [&](int buf, int t) {
        int k0 = t << 6;
#pragma unroll
        for (int i = 0; i < 4; i++) {
            int rb = w * 32 + i * 8;              // 8 rows per gl_lds
            gl_lds(A  + (long)(m0 + rb + srow8) * LD + k0 + swz, &lds[buf][0][rb * 64]);
            gl_lds(Bm + (long)(n0 + rb + srow8) * LD + k0 + swz, &lds[buf][1][rb * 64]);
        }
    };

    STAGE(0, 0);
    STAGE(1, 1);
    asm volatile("s_waitcnt vmcnt(8)" ::: "memory");
    __builtin_amdgcn_s_barrier();

    for (int t = 0; t < NT; t++) {
        const bf16* bufA = &lds[t & 1][0][0];
        const bf16* bufB = &lds[t & 1][1][0];

        bfrag a0[4][2], b0[4][2];
#pragma unroll
        for (int mi = 0; mi < 4; mi++)
#pragma unroll
            for (int kk = 0; kk < 2; kk++)
                a0[mi][kk] = *(const bfrag*)(bufA + (wm * 128 + mi * 16 + c) * 64
                                                  + 8 * ((4 * kk + g) ^ cx));
#pragma unroll
        for (int ni = 0; ni < 4; ni++)
#pragma unroll
            for (int kk = 0; kk < 2; kk++)
                b0[ni][kk] = *(const bfrag*)(bufB + (wn * 64 + ni * 16 + c) * 64
                                                  + 8 * ((4 * kk + g) ^ cx));
        asm volatile("s_waitcnt lgkmcnt(0)" ::: "memory");
        __builtin_amdgcn_sched_barrier(0);
        __builtin_amdgcn_s_setprio(1);
#pragma unroll
        for (int mi = 0; mi < 4; mi++)
#pragma unroll
            for (int ni = 0; ni < 4; ni++) {
                acc[mi][ni] = __builtin_amdgcn_mfma_f32_16x16x32_bf16(
                    a0[mi][0], b0[ni][0], acc[mi][ni], 0, 0, 0);
                acc[mi][ni] = __builtin_amdgcn_mfma_f32_16x16x32_bf16(
                    a0[mi][1], b0[ni][1], acc[mi][ni], 0, 0, 0);
            }
        __builtin_amdgcn_s_setprio(0);

        bfrag a1[4][2];
#pragma unroll
        for (int mi = 0; mi < 4; mi++)
#pragma unroll
            for (int kk = 0; kk < 2; kk++)
                a1[mi][kk] = *(const bfrag*)(bufA + (wm * 128 + (mi + 4) * 16 + c) * 64
                                                  + 8 * ((4 * kk + g) ^ cx));
        asm volatile("s_waitcnt lgkmcnt(0)" ::: "memory");
        __builtin_amdgcn_sched_barrier(0);
        __builtin_amdgcn_s_setprio(1);
#pragma unroll
        for (int mi = 0; mi < 4; mi++)
#pragma unroll
            for (int ni = 0; ni < 4; ni++) {
                acc[mi + 4][ni] = __builtin_amdgcn_mfma_f32_16x16x32_bf16(
                    a1[mi][0], b0[ni][0], acc[mi + 4][ni], 0, 0, 0);
                acc[mi + 4][ni] = __builtin_amdgcn_mfma_f32_16x16x32_bf16(
                    a1[mi][1], b0[ni][1], acc[mi + 4][ni], 0, 0, 0);
            }
        __builtin_amdgcn_s_setprio(0);

        __builtin_amdgcn_s_barrier();
        if (t + 2 < NT) {
            STAGE(t & 1, t + 2);
            asm volatile("s_waitcnt vmcnt(8)" ::: "memory");
        } else if (t + 1 < NT) {
            asm volatile("s_waitcnt vmcnt(0)" ::: "memory");
        }
        __builtin_amdgcn_s_barrier();
    }

#pragma unroll
    for (int mi = 0; mi < 8; mi++)
#pragma unroll
        for (int ni = 0; ni < 4; ni++) {
            long row = m0 + wm * 128 + mi * 16 + 4 * g;
            long col = n0 + wn * 64 + ni * 16 + c;
#pragma unroll
            for (int r = 0; r < 4; r++)
                stf(&C[(row + r) * N + col], acc[mi][ni][r]);
        }
}

// ---------------------------------------------------------------------------
// RoPE v2 + per-row L2 norm + sqk*sqrt(dm); QKVb bf16 layout [row][h*192+e].
// Block = (h, b, 64-wide t-tile); 4 waves x 16 rows. V staged in LDS [64][66]
// then written as 16 contiguous t-elems per thread -> coalesced Vt.
// Qb carries sdpa sqrt(dm)=32 AND log2e (exp2 path in attn).
// ---------------------------------------------------------------------------
__global__ __launch_bounds__(256)
void rope_norm_qk(const bf16* __restrict__ QKVb, const float* __restrict__ sqk,
                  bf16* __restrict__ Qb, bf16* __restrict__ Kb, bf16* __restrict__ Vt)
{
    __shared__ unsigned short vbuf[64][66];   // pad 66 -> <=4-way on gather

    int bid  = blockIdx.x;                // 0..2047
    int h    = bid >> 7;                  // / (B_*32)
    int rem  = bid & 127;
    int b    = rem >> 5;
    int tile = rem & 31;
    int w    = threadIdx.x >> 6;
    int lane = threadIdx.x & 63;

    int   j       = lane & 31;
    // inv_rev = 10000^(-j/32) / (2*pi);  log2(10000)/32 = 0.41524101
    float inv_rev = fexp2(-(float)j * 0.41524101f) * 0.15915494f;
    float se      = sqk[h * 64 + lane] * 32.f;   // sqk * sqrt(dm)

#pragma unroll 1
    for (int i = 0; i < 16; i++) {
        int tl = i * 4 + w;               // 0..63
        int t  = tile * 64 + tl;
        long row = (long)b * T_ + t;
        const bf16* base = QKVb + row * 3072 + h * 192;
        float q = ldf(base + lane);
        float k = ldf(base + 64 + lane);
        unsigned short vb = ((const unsigned short*)base)[128 + lane];

        float ar = (float)t * inv_rev;
        ar = ar - floorf(ar);                       // revolutions in [0,1)
        float s  = __builtin_amdgcn_sinf(ar);
        float cc = __builtin_amdgcn_cosf(ar);

        float qp = __shfl_xor(q, 32, 64);
        float kp = __shfl_xor(k, 32, 64);
        float sgn = (lane < 32) ? -1.f : 1.f;
        float qr = q * cc + sgn * qp * s;
        float kr = k * cc + sgn * kp * s;

        float qs = wave_sum(qr * qr);
        float ks = wave_sum(kr * kr);

        long idx = ((long)h * NROW + row) * 64 + lane;
        Qb[idx] = __float2bfloat16(qr * rsqrtf(qs) * se * EXPB);  // 32*log2e
        Kb[idx] = __float2bfloat16(kr * rsqrtf(ks) * se);
        vbuf[tl][lane] = vb;
    }
    __syncthreads();

    // V transpose write: thread -> (d = tid>>2, 16 t's at seg*16)
    int d   = threadIdx.x >> 2;
    int seg = threadIdx.x & 3;
    union { bfrag f; unsigned short s[8]; } o0, o1;
#pragma unroll
    for (int jj = 0; jj < 8; jj++) {
        o0.s[jj] = vbuf[seg * 16 + jj][d];
        o1.s[jj] = vbuf[seg * 16 + 8 + jj][d];
    }
    bf16* dst = Vt + ((long)(h * B_ + b) * 64 + d) * T_ + tile * 64 + seg * 16;
    *(bfrag*)dst       = o0.f;
    *(bfrag*)(dst + 8) = o1.f;
}

// ---------------------------------------------------------------------------
// MFMA flash attention, exp2 fixed-shift softmax (C-init = -EXPB), paired
// q-tiles. 8-wave blocks (512 thr), K/V LDS staging shared by 8 waves.
// Per-wave ranges differ by <=1 iteration (nA = 2*blk + (w>=4)); actA/actB
// guards wave-uniform. Heavy/light blk interleave; XCD swizzle.
// ---------------------------------------------------------------------------
__global__ __launch_bounds__(512)
void attn_mfma(const bf16* __restrict__ Qb, const bf16* __restrict__ Kb,
               const bf16* __restrict__ Vt, bf16* __restrict__ O)
{
    __shared__ bf16 kv[2][2][64 * 64];    // [buf][K|V][row*64 + chunk-swizzled]

    int orig   = blockIdx.x;              // 0..511
    int xcd    = orig & 7;
    int rest   = orig >> 3;               // 0..63
    int bh     = xcd * 8 + (rest & 7);    // 8 (b,h) per XCD -> 4MiB K/V in L2
    int blkraw = rest >> 3;               // 0..7
    int blk    = (blkraw & 1) ? (7 - (blkraw >> 1)) : (blkraw >> 1);
    int w      = threadIdx.x >> 6;        // 0..7
    int pr     = blk * 8 + w;             // 0..63
    int h = bh >> 2, b = bh & 3;

    int lane = threadIdx.x & 63;
    int g = lane >> 4, c = lane & 15;

    const bf16* kbase = Kb + ((long)h * NROW + (long)b * T_) * 64;
    const bf16* vbase = Vt + (long)(h * B_ + b) * 64 * (long)T_;

    int q0A = pr * 16, q0B = (127 - pr) * 16;
    const bf16* qbA = Qb + ((long)h * NROW + (long)b * T_ + q0A) * 64;
    const bf16* qbB = Qb + ((long)h * NROW + (long)b * T_ + q0B) * 64;
    bfrag qfA0 = *(const bfrag*)(qbA + (long)c * 64 + 8 * g);
    bfrag qfA1 = *(const bfrag*)(qbA + (long)c * 64 + 32 + 8 * g);
    bfrag qfB0 = *(const bfrag*)(qbB + (long)c * 64 + 8 * g);
    bfrag qfB1 = *(const bfrag*)(qbB + (long)c * 64 + 32 + 8 * g);

    const f4 CINIT = {-EXPB, -EXPB, -EXPB, -EXPB};

    f4 otA[4] = {{0,0,0,0},{0,0,0,0},{0,0,0,0},{0,0,0,0}};
    f4 otB[4] = {{0,0,0,0},{0,0,0,0},{0,0,0,0},{0,0,0,0}};
    float lA = 0.f, lB = 0.f;

    const int nA = pr >> 2;               // 2*blk + (w>=4)
    const int nB = 31 - nA;
    const int KTblk = 31 - 2 * blk;       // block-uniform loop bound (max nB)
    int qgA = q0A + c, qgB = q0B + c;

    const int srow8  = lane >> 3;                 // 0..7
    const int swz    = 8 * ((lane & 7) ^ srow8);  // swizzled source chunk

    auto STAGE = [&](int buf, int kt) {
        int k0 = kt * 64;
        int row = w * 8 + srow8;                  // 8 waves cover 64 rows
        gl_lds(kbase + (long)(k0 + row) * 64 + swz, &kv[buf][0][w * 8 * 64]);
        gl_lds(vbase + (long)row * T_ + k0 + swz,   &kv[buf][1][w * 8 * 64]);
    };

    STAGE(0, 0);
    __syncthreads();

    const int cx = c & 7;

    for (int kt = 0; kt <= KTblk; kt++) {
        int buf = kt & 1;
        if (kt < KTblk) STAGE(buf ^ 1, kt + 1);

        const bf16* Kl = &kv[buf][0][0];
        const bf16* Vl = &kv[buf][1][0];
        int k0 = kt * 64;
        bool actA = (kt <= nA);           // wave-uniform
        bool actB = (kt <= nB);           // wave-uniform
        unsigned wvA[8], wvB[8];

        if (actA || actB) {
#pragma unroll
            for (int kb = 0; kb < 4; kb++) {
                const bf16* kr = Kl + (16 * kb + c) * 64;
                bfrag ka = *(const bfrag*)(kr + 8 * (g ^ cx));
                bfrag kc = *(const bfrag*)(kr + 8 * ((g | 4) ^ cx));

                if (actB) {
                    f4 sB = __builtin_amdgcn_mfma_f32_16x16x32_bf16(ka, qfB0, CINIT, 0, 0, 0);
                    sB = __builtin_amdgcn_mfma_f32_16x16x32_bf16(kc, qfB1, sB, 0, 0, 0);
                    if (kt == nB) {
#pragma unroll
                        for (int r = 0; r < 4; r++)
                            if (k0 + 16 * kb + 4 * g + r > qgB) sB[r] = -1e30f;
                    }
                    float eB0 = fexp2(sB[0]), eB1 = fexp2(sB[1]);
                    float eB2 = fexp2(sB[2]), eB3 = fexp2(sB[3]);
                    lB += (eB0 + eB1) + (eB2 + eB3);
                    wvB[2 * kb]     = pk2t(eB0, eB1);
                    wvB[2 * kb + 1] = pk2t(eB2, eB3);
                }

                if (actA) {
                    f4 sA = __builtin_amdgcn_mfma_f32_16x16x32_bf16(ka, qfA0, CINIT, 0, 0, 0);
                    sA = __builtin_amdgcn_mfma_f32_16x16x32_bf16(kc, qfA1, sA, 0, 0, 0);
                    if (kt == nA) {
#pragma unroll
                        for (int r = 0; r < 4; r++)
                            if (k0 + 16 * kb + 4 * g + r > qgA) sA[r] = -1e30f;
                    }
                    float eA0 = fexp2(sA[0]), eA1 = fexp2(sA[1]);
                    float eA2 = fexp2(sA[2]), eA3 = fexp2(sA[3]);
                    lA += (eA0 + eA1) + (eA2 + eA3);
                    wvA[2 * kb]     = pk2t(eA0, eA1);
                    wvA[2 * kb + 1] = pk2t(eA2, eA3);
                }
            }

            // PV: two 32-key halves; B-frag = P^T via lane exchange; V from LDS
#pragma unroll
            for (int p = 0; p < 2; p++) {
                int s0l = c + 32 * (g & 1), s1l = s0l + 16;
                bool hi = (g >= 2);

                union { bfrag f; unsigned u[4]; } pfB, pfA;
                if (actB) {
                    unsigned Bb0 = (unsigned)__shfl((int)wvB[4 * p + 0], s0l, 64);
                    unsigned Bb1 = (unsigned)__shfl((int)wvB[4 * p + 1], s0l, 64);
                    unsigned Bb2 = (unsigned)__shfl((int)wvB[4 * p + 2], s0l, 64);
                    unsigned Bb3 = (unsigned)__shfl((int)wvB[4 * p + 3], s0l, 64);
                    unsigned Bb4 = (unsigned)__shfl((int)wvB[4 * p + 0], s1l, 64);
                    unsigned Bb5 = (unsigned)__shfl((int)wvB[4 * p + 1], s1l, 64);
                    unsigned Bb6 = (unsigned)__shfl((int)wvB[4 * p + 2], s1l, 64);
                    unsigned Bb7 = (unsigned)__shfl((int)wvB[4 * p + 3], s1l, 64);
                    pfB.u[0] = hi ? Bb2 : Bb0;
                    pfB.u[1] = hi ? Bb3 : Bb1;
                    pfB.u[2] = hi ? Bb6 : Bb4;
                    pfB.u[3] = hi ? Bb7 : Bb5;
                }
                if (actA) {
                    unsigned Ab0 = (unsigned)__shfl((int)wvA[4 * p + 0], s0l, 64);
                    unsigned Ab1 = (unsigned)__shfl((int)wvA[4 * p + 1], s0l, 64);
                    unsigned Ab2 = (unsigned)__shfl((int)wvA[4 * p + 2], s0l, 64);
                    unsigned Ab3 = (unsigned)__shfl((int)wvA[4 * p + 3], s0l, 64);
                    unsigned Ab4 = (unsigned)__shfl((int)wvA[4 * p + 0], s1l, 64);
                    unsigned Ab5 = (unsigned)__shfl((int)wvA[4 * p + 1], s1l, 64);
                    unsigned Ab6 = (unsigned)__shfl((int)wvA[4 * p + 2], s1l, 64);
                    unsigned Ab7 = (unsigned)__shfl((int)wvA[4 * p + 3], s1l, 64);
                    pfA.u[0] = hi ? Ab2 : Ab0;
                    pfA.u[1] = hi ? Ab3 : Ab1;
                    pfA.u[2] = hi ? Ab6 : Ab4;
                    pfA.u[3] = hi ? Ab7 : Ab5;
                }

#pragma unroll
                for (int dblk = 0; dblk < 4; dblk++) {
                    bfrag vf = *(const bfrag*)(Vl + (16 * dblk + c) * 64
                                                  + 8 * (((p << 2) | g) ^ cx));
                    if (actB)
                        otB[dblk] = __builtin_amdgcn_mfma_f32_16x16x32_bf16(vf, pfB.f, otB[dblk], 0, 0, 0);
                    if (actA)
                        otA[dblk] = __builtin_amdgcn_mfma_f32_16x16x32_bf16(vf, pfA.f, otA[dblk], 0, 0, 0);
                }
            }
        }
        __syncthreads();
    }

    lA += __shfl_xor(lA, 16, 64); lA += __shfl_xor(lA, 32, 64);
    lB += __shfl_xor(lB, 16, 64); lB += __shfl_xor(lB, 32, 64);

    float invA = 1.f / lA, invB = 1.f / lB;
    long orowA = (long)(b * T_ + q0A + c) * DM + h * 64;
    long orowB = (long)(b * T_ + q0B + c) * DM + h * 64;
#pragma unroll
    for (int dblk = 0; dblk < 4; dblk++)
#pragma unroll
        for (int r = 0; r < 4; r++) {
            O[orowA + 16 * dblk + 4 * g + r] = __float2bfloat16(otA[dblk][r] * invA);
            O[orowB + 16 * dblk + 4 * g + r] = __float2bfloat16(otB[dblk][r] * invB);
        }
}

// ---------------------------------------------------------------------------
// Out = justnorm(A + lr*(Bn - A)); t-input = Tt (+ Tt2 if non-null, summed).
// Vectorized: thread handles 4 contiguous elems at tid*4.
// ---------------------------------------------------------------------------
template <typename TX, typename TT>
__global__ __launch_bounds__(256)
void lerp_norm(const TX* __restrict__ X, const TT* __restrict__ Tt,
               const TT* __restrict__ Tt2, const float* __restrict__ alpha,
               float ascale, float* __restrict__ OutF, bf16* __restrict__ OutB)
{
    long row = blockIdx.x;
    int t4 = threadIdx.x * 4;
    const TX* xr = X  + row * DM + t4;
    const TT* tr = Tt + row * DM + t4;

    float xs[4], ts[4];
    ld4(xr, xs);
    ld4(tr, ts);
    if (Tt2) {
        float t2[4];
        ld4(Tt2 + row * DM + t4, t2);
#pragma unroll
        for (int i = 0; i < 4; i++) ts[i] += t2[i];
    }
    float sx = 0.f, st = 0.f;
#pragma unroll
    for (int i = 0; i < 4; i++) { sx += xs[i] * xs[i]; st += ts[i] * ts[i]; }
    sx = block_sum(sx);
    st = block_sum(st);
    float ix = rsqrtf(sx), it = rsqrtf(st);

    float4 al = *(const float4*)(alpha + t4);
    float av[4] = {al.x, al.y, al.z, al.w};
    float ys[4], sy = 0.f;
#pragma unroll
    for (int i = 0; i < 4; i++) {
        float a  = xs[i] * ix;
        float bn = ts[i] * it;
        float lr = fabsf(av[i] * ascale);
        ys[i] = a + lr * (bn - a);
        sy += ys[i] * ys[i];
    }
    sy = block_sum(sy);
    float iy = rsqrtf(sy);
#pragma unroll
    for (int i = 0; i < 4; i++) ys[i] *= iy;

    if (OutF) *(float4*)(OutF + row * DM + t4) = make_float4(ys[0], ys[1], ys[2], ys[3]);
    if (OutB) {
        uint2 o;
        o.x = pk2(ys[0], ys[1]);
        o.y = pk2(ys[2], ys[3]);
        *(uint2*)(OutB + row * DM + t4) = o;
    }
}

// ---------------------------------------------------------------------------
// tn = justnorm(suv*32*uv_row[8192]); res = u*silu(v). Vectorized single-pass.
// ---------------------------------------------------------------------------
__global__ __launch_bounds__(256)
void mlp_act(const bf16* __restrict__ UV, const float* __restrict__ suv,
             bf16* __restrict__ R)
{
    long row = blockIdx.x;
    const bf16* ur = UV + row * 8192;
    int t8 = threadIdx.x * 8;

    float f[4][8];
    float ss = 0.f;
#pragma unroll
    for (int ch = 0; ch < 4; ch++) {
        bfrag d = *(const bfrag*)(ur + ch * 2048 + t8);
        const float4* sp = (const float4*)(suv + ch * 2048 + t8);
        float4 s0 = sp[0], s1 = sp[1];
        float sv[8] = {s0.x, s0.y, s0.z, s0.w, s1.x, s1.y, s1.z, s1.w};
#pragma unroll
        for (int e = 0; e < 8; e++) {
            unsigned short us = __builtin_bit_cast(unsigned short, (short)d[e]);
            float v = __builtin_bit_cast(float, (unsigned)us << 16) * sv[e] * 32.f;
            f[ch][e] = v;
            ss += v * v;
        }
    }
    ss = block_sum(ss);
    float inv = rsqrtf(ss);

#pragma unroll
    for (int ch = 0; ch < 2; ch++) {
        union { bfrag f; unsigned u[4]; } o;
#pragma unroll
        for (int e = 0; e < 8; e += 2) {
            float u0 = f[ch][e]     * inv, u1 = f[ch][e + 1]     * inv;
            float v0 = f[ch + 2][e] * inv, v1 = f[ch + 2][e + 1] * inv;
            float r0 = u0 * v0 / (1.f + __expf(-v0));
            float r1 = u1 * v1 / (1.f + __expf(-v1));
            o.u[e >> 1] = pk2(r0, r1);
        }
        *(bfrag*)(R + row * 4096 + ch * 2048 + t8) = o.f;
    }
}

// ---------------------------------------------------------------------------
extern "C" void kernel_launch(void* const* d_in, const int* in_sizes, int n_in,
                              void* d_out, int out_size, void* d_ws, size_t ws_size,
                              hipStream_t stream)
{
    const float* x          = (const float*)d_in[0];
    const float* qkv_w      = (const float*)d_in[1];
    const float* sqk        = (const float*)d_in[2];
    const float* W_O        = (const float*)d_in[3];
    const float* Wu         = (const float*)d_in[4];
    const float* Wv         = (const float*)d_in[5];
    const float* attn_alpha = (const float*)d_in[6];
    const float* mlp_alpha  = (const float*)d_in[7];
    const float* suv        = (const float*)d_in[8];
    float* out = (float*)d_out;

    const long MiB = 1048576;
    char* ws = (char*)d_ws;
    bf16*  Wub   = (bf16*) (ws + 0 * MiB);    // 16MB, free region (step 0 -> 7)
    bf16*  Wvb   = (bf16*) (ws + 16 * MiB);   // 8MB  (step 0 -> 8)
    bf16*  x1b   = (bf16*) (ws + 32 * MiB);
    bf16*  QKVb  = (bf16*) (ws + 48 * MiB);
    bf16*  tbuf  = (bf16*) (ws + 48 * MiB);   // 16MB, after QKVb dead
    bf16*  uv    = (bf16*) (ws + 48 * MiB);   // half: [4096][8192]
    bf16*  t2a   = (bf16*) (ws + 48 * MiB);   // 16MB, after uv dead
    bf16*  t2b   = (bf16*) (ws + 64 * MiB);   // 16MB
    bf16*  xb    = (bf16*) (ws + 144 * MiB);  // DEAD after step 1 (Qb aliases)
    bf16*  Qb    = (bf16*) (ws + 144 * MiB);
    bf16*  Kb    = (bf16*) (ws + 160 * MiB);
    bf16*  Vt    = (bf16*) (ws + 176 * MiB);
    bf16*  res   = (bf16*) (ws + 112 * MiB);  // [8192][4096]
    bf16*  qkvwb = (bf16*) (ws + 192 * MiB);
    bf16*  attno = (bf16*) (ws + 192 * MiB);
    bf16*  Wob   = (bf16*) (ws + 208 * MiB);
    // peak 210 MiB

    // 0) ALL f32->bf16 converts in one fused launch (Wub/Wvb in free region,
    //    no aliasing with rope outputs)
    convert_all_k<<<12288, 256, 0, stream>>>(x, xb, qkv_w, qkvwb, W_O, Wob,
                                             Wu, Wub, Wv, Wvb);

    // 1) QKV projection -> bf16 [8192][3072]  (256^2 pipelined gemm)
    gemm_bf16_256<bf16><<<dim3(12, 32, 1), 512, 0, stream>>>(
        xb, qkvwb, QKVb, NROW, 3072, DM, DM, 0L);

    // 2) RoPE v2 + justnorm + scaling -> Qb/Kb/Vt (coalesced Vt via LDS)
    rope_norm_qk<<<H_ * B_ * (T_ / 64), 256, 0, stream>>>(QKVb, sqk, Qb, Kb, Vt);

    // 3) MFMA flash attention (8-wave blocks) -> attno bf16
    attn_mfma<<<512, 512, 0, stream>>>(Qb, Kb, Vt, attno);

    // 4) W_O projection -> tbuf bf16 (128^2 kernel; QKVb region dead)
    gemm_bf16<bf16><<<dim3(8, 64), 256, 0, stream>>>(attno, Wob, tbuf, NROW, DM, DM);

    // 5) attention residual lerp-norm -> x1b (A from pristine fp32 x)
    lerp_norm<float, bf16><<<NROW, 256, 0, stream>>>(
        x, tbuf, (const bf16*)nullptr, attn_alpha, 1.6f, (float*)nullptr, x1b);

    // 6) MLP in two M-halves: uv(half) = x1b @ Wu^T -> bf16; act -> res
    for (int half = 0; half < 2; half++) {
        gemm_bf16_256<bf16><<<dim3(32, 16, 1), 512, 0, stream>>>(
            x1b + (long)half * 4096 * DM, Wub, uv, 4096, 8 * DM, DM, DM, 0L);
        mlp_act<<<4096, 256, 0, stream>>>(uv, suv, res + (long)half * 4096 * 4096);
    }

    // 7) t2 = res @ Wv^T, split-K=2 -> bf16 partials (uv dead; t2a/t2b reuse)
    gemm_bf16_256<bf16><<<dim3(4, 32, 2), 512, 0, stream>>>(
        res, Wvb, t2a, NROW, DM, 2048, 4 * DM, 8388608L);

    // 8) MLP residual lerp-norm -> out (t = t2a + t2b)
    lerp_norm<bf16, bf16><<<NROW, 256, 0, stream>>>(
        x1b, t2a, t2b, mlp_alpha, 0.05f, out, (bf16*)nullptr);
}

// Round 23
// 481.297 us; speedup vs baseline: 1.0341x; 1.0208x over previous
//
#include <hip/hip_runtime.h>
#include <hip/hip_bf16.h>

// nGPT-style transformer layer, MI355X. Round 22: single full-M Wu GEMM +
// single in-place mlp_act (uv[8192][8192] in the 48-176MiB region; act
// writes res into cols 0..4096 of its own row; Wv reads it with LDA=8192,
// LDB=4096). 9 -> 7 dispatches. Rest = round-21 best-known (491.3 us).
// B=4 T=2048 dm=1024 H=16 di=64.
//
// Workspace arena (peak 210 MiB). Aliasing is ORDER-SENSITIVE; launch order
// is the contract. Lifetimes:
//   [0,  16M)  Wub   (cvt step0 -> Wu gemm step6)
//   [16, 24M)  Wvb   (cvt step0 -> Wv gemm step8)
//   [32, 48M)  x1b   (lerp1 step5 -> Wu gemm step6, lerp2 step9)
//   [48, 96M)  QKVb  (gemm step1 -> rope step2)          } all dead before
//   [48, 64M)  tbuf  (W_O step4 -> lerp1 step5)          } uv write step6
//   [144,160M) xb (cvt0 -> step1) then Qb (rope2 -> attn3)
//   [160,176M) Kb (rope2 -> attn3)
//   [48,176M)  uv [8192][8192] (Wu step6 -> act step7 in-place -> Wv step8)
//   [176,192M) Vt (rope2 -> attn3), then t2a (Wv step8 -> lerp2 step9)
//   [192,208M) qkvwb (cvt0 -> step1), attno (attn3 -> W_O step4),
//              then t2b (Wv step8 -> lerp2 step9)
//   [208,210M) Wob (cvt0 -> W_O step4)

#define B_   4
#define T_   2048
#define DM   1024
#define H_   16
#define DI   64
#define NROW (B_ * T_)   // 8192

using bf16 = __hip_bfloat16;
typedef __attribute__((ext_vector_type(8))) short bfrag;   // 8 bf16 (4 VGPR)
typedef __attribute__((ext_vector_type(4))) float f4;

#define EXPB 46.166241f   // 32 * log2(e): sdpa-scale x log2e, folded into Q

__device__ __forceinline__ float ldf(const float* p) { return *p; }
__device__ __forceinline__ float ldf(const bf16* p)  { return __bfloat162float(*p); }
__device__ __forceinline__ void  stf(float* p, float v) { *p = v; }
__device__ __forceinline__ void  stf(bf16* p, float v)  { *p = __float2bfloat16(v); }

__device__ __forceinline__ unsigned short bfbits(float a) {
    bf16 h = __float2bfloat16(a);
    return __builtin_bit_cast(unsigned short, h);
}
__device__ __forceinline__ unsigned pk2(float a, float b) {    // RNE (converts)
    return (unsigned)bfbits(a) | ((unsigned)bfbits(b) << 16);
}
// truncation pack: hi16(a) | hi16(b)<<16 in ONE v_perm_b32 (P in [0,1]).
__device__ __forceinline__ unsigned pk2t(float a, float b) {
    return __builtin_amdgcn_perm(__builtin_bit_cast(unsigned, b),
                                 __builtin_bit_cast(unsigned, a), 0x07060302u);
}

// fast exp2: single v_exp_f32
__device__ __forceinline__ float fexp2(float x) {
    return __builtin_amdgcn_exp2f(x);
}

// vectorized 4-element loads (contiguous per thread)
__device__ __forceinline__ void ld4(const float* p, float* o) {
    float4 v = *(const float4*)p;
    o[0] = v.x; o[1] = v.y; o[2] = v.z; o[3] = v.w;
}
__device__ __forceinline__ void ld4(const bf16* p, float* o) {
    ushort4 v = *(const ushort4*)p;
    o[0] = __builtin_bit_cast(float, (unsigned)v.x << 16);
    o[1] = __builtin_bit_cast(float, (unsigned)v.y << 16);
    o[2] = __builtin_bit_cast(float, (unsigned)v.z << 16);
    o[3] = __builtin_bit_cast(float, (unsigned)v.w << 16);
}

__device__ __forceinline__ float wave_sum(float v) {
#pragma unroll
    for (int off = 32; off; off >>= 1) v += __shfl_xor(v, off, 64);
    return v;
}

__device__ __forceinline__ float block_sum(float v) {
    __shared__ float sm[4];
    int lane = threadIdx.x & 63, w = threadIdx.x >> 6;
    v = wave_sum(v);
    __syncthreads();
    if (lane == 0) sm[w] = v;
    __syncthreads();
    return sm[0] + sm[1] + sm[2] + sm[3];
}

// async global->LDS, 16B per lane; LDS dest = wave-uniform base + lane*16
typedef __attribute__((address_space(1))) const void g_void;
typedef __attribute__((address_space(3))) void l_void;
__device__ __forceinline__ void gl_lds(const void* g, void* l) {
    __builtin_amdgcn_global_load_lds((g_void*)g, (l_void*)l, 16, 0, 0);
}

// ---------------------------------------------------------------------------
// Fused f32 -> bf16 converts: 5 segments, one launch. Each block converts
// 2048 contiguous elements of its segment (8 per thread). Segment block
// counts: x 4096 | qkv_w 1536 | W_O 512 | Wu 4096 | Wv 2048  (total 12288).
// ---------------------------------------------------------------------------
__global__ __launch_bounds__(256)
void convert_all_k(const float* __restrict__ x,    bf16* __restrict__ xb,
                   const float* __restrict__ qkvw, bf16* __restrict__ qkvwb,
                   const float* __restrict__ wo,   bf16* __restrict__ wob,
                   const float* __restrict__ wu,   bf16* __restrict__ wub,
                   const float* __restrict__ wv,   bf16* __restrict__ wvb)
{
    int bid = blockIdx.x;
    const float* src; bf16* dst; long base;
    if (bid < 4096)       { src = x;    dst = xb;    base = (long)bid * 2048; }
    else if (bid < 5632)  { src = qkvw; dst = qkvwb; base = (long)(bid - 4096) * 2048; }
    else if (bid < 6144)  { src = wo;   dst = wob;   base = (long)(bid - 5632) * 2048; }
    else if (bid < 10240) { src = wu;   dst = wub;   base = (long)(bid - 6144) * 2048; }
    else                  { src = wv;   dst = wvb;   base = (long)(bid - 10240) * 2048; }

    long i = base + (long)threadIdx.x * 8;
    float4 a = *(const float4*)(src + i);
    float4 b = *(const float4*)(src + i + 4);
    union { bfrag f; unsigned u[4]; } o;
    o.u[0] = pk2(a.x, a.y); o.u[1] = pk2(a.z, a.w);
    o.u[2] = pk2(b.x, b.y); o.u[3] = pk2(b.z, b.w);
    *(bfrag*)(dst + i) = o.f;
}

// ---------------------------------------------------------------------------
// C = A * B^T, 128x128 tile, BK=32, 4 waves, m97 structure (W_O: N=1024).
// ---------------------------------------------------------------------------
template <typename TC>
__global__ __launch_bounds__(256)
void gemm_bf16(const bf16* __restrict__ A, const bf16* __restrict__ Bm,
               TC* __restrict__ C, int M, int N, int K)
{
    __shared__ bf16 lds[2][2][128 * 32];   // [buf][A|B][row*32+k]
    const int tid  = threadIdx.x;
    const int w    = tid >> 6, lane = tid & 63;
    const int g    = lane >> 4, c = lane & 15;
    const int m0   = blockIdx.y * 128, n0 = blockIdx.x * 128;
    const int wm   = w >> 1, wn = w & 1;

    const int srow = (lane >> 2);        // 0..15 within chunk
    const int skc  = 8 * (lane & 3);     // k elem offset 0,8,16,24

    f4 acc[4][4] = {{{0,0,0,0}}};

    const int NT = K >> 5;               // K/32 steps

#pragma unroll
    for (int q = 0; q < 2; q++) {
        int cidx = w * 2 + q;            // 0..7, covers rows [16*cidx,+16)
        int row  = 16 * cidx + srow;
        gl_lds(A + (long)(m0 + row) * K + skc, &lds[0][0][cidx * 512]);
        gl_lds(Bm + (long)(n0 + row) * K + skc, &lds[0][1][cidx * 512]);
    }
    __syncthreads();

    for (int t = 0; t < NT; t++) {
        int cur = t & 1;
        if (t + 1 < NT) {
            int k0 = (t + 1) << 5;
#pragma unroll
            for (int q = 0; q < 2; q++) {
                int cidx = w * 2 + q;
                int row  = 16 * cidx + srow;
                gl_lds(A + (long)(m0 + row) * K + k0 + skc, &lds[cur ^ 1][0][cidx * 512]);
                gl_lds(Bm + (long)(n0 + row) * K + k0 + skc, &lds[cur ^ 1][1][cidx * 512]);
            }
        }
        const bf16* bufA = &lds[cur][0][0];
        const bf16* bufB = &lds[cur][1][0];
        bfrag af[4], bb[4];
#pragma unroll
        for (int mi = 0; mi < 4; mi++)
            af[mi] = *(const bfrag*)(bufA + (64 * wm + 16 * mi + c) * 32 + 8 * g);
#pragma unroll
        for (int ni = 0; ni < 4; ni++)
            bb[ni] = *(const bfrag*)(bufB + (64 * wn + 16 * ni + c) * 32 + 8 * g);
#pragma unroll
        for (int mi = 0; mi < 4; mi++)
#pragma unroll
            for (int ni = 0; ni < 4; ni++)
                acc[mi][ni] = __builtin_amdgcn_mfma_f32_16x16x32_bf16(
                    af[mi], bb[ni], acc[mi][ni], 0, 0, 0);
        __syncthreads();
    }

#pragma unroll
    for (int mi = 0; mi < 4; mi++)
#pragma unroll
        for (int ni = 0; ni < 4; ni++) {
            long row = m0 + 64 * wm + 16 * mi + 4 * g;
            long col = n0 + 64 * wn + 16 * ni + c;
#pragma unroll
            for (int r = 0; r < 4; r++)
                stf(&C[(row + r) * N + col], acc[mi][ni][r]);
        }
}

// ---------------------------------------------------------------------------
// C = A * B^T, 256x256 tile, BK=64, 8 waves (2M x 4N), 128KB LDS dbuf.
// 2-cluster schedule: counted vmcnt(8), (row&7) chunk-XOR swizzle,
// setprio around MFMA clusters. LDA/LDB = leading dims of A and B (>= K);
// blockIdx.z advances A/B by K elements (split-K) and C by sCz elements.
// M,N %256==0, K %64==0, K>=128.
// ---------------------------------------------------------------------------
template <typename TC>
__global__ __launch_bounds__(512, 2)
void gemm_bf16_256(const bf16* __restrict__ A, const bf16* __restrict__ Bm,
                   TC* __restrict__ C, int M, int N, int K, int LDA, int LDB,
                   long sCz)
{
    A  += (long)blockIdx.z * K;
    Bm += (long)blockIdx.z * K;
    C  += (long)blockIdx.z * sCz;

    __shared__ bf16 lds[2][2][256 * 64];   // 128 KiB
    const int tid  = threadIdx.x;
    const int w    = tid >> 6, lane = tid & 63;
    const int g    = lane >> 4, c = lane & 15;
    const int m0   = blockIdx.y * 256, n0 = blockIdx.x * 256;
    const int wm   = w & 1, wn = w >> 1;          // 2M x 4N wave grid
    const int srow8 = lane >> 3;                  // 0..7
    const int swz   = 8 * ((lane & 7) ^ srow8);   // pre-swizzled source chunk
    const int cx    = c & 7;

    f4 acc[8][4] = {{{0,0,0,0}}};

    const int NT = K >> 6;

    auto STAGE = [&](int buf, int t) {
        int k0 = t << 6;
#pragma unroll
        for (int i = 0; i < 4; i++) {
            int rb = w * 32 + i * 8;              // 8 rows per gl_lds
            gl_lds(A  + (long)(m0 + rb + srow8) * LDA + k0 + swz, &lds[buf][0][rb * 64]);
            gl_lds(Bm + (long)(n0 + rb + srow8) * LDB + k0 + swz, &lds[buf][1][rb * 64]);
        }
    };

    STAGE(0, 0);
    STAGE(1, 1);
    asm volatile("s_waitcnt vmcnt(8)" ::: "memory");
    __builtin_amdgcn_s_barrier();

    for (int t = 0; t < NT; t++) {
        const bf16* bufA = &lds[t & 1][0][0];
        const bf16* bufB = &lds[t & 1][1][0];

        bfrag a0[4][2], b0[4][2];
#pragma unroll
        for (int mi = 0; mi < 4; mi++)
#pragma unroll
            for (int kk = 0; kk < 2; kk++)
                a0[mi][kk] = *(const bfrag*)(bufA + (wm * 128 + mi * 16 + c) * 64
                                                  + 8 * ((4 * kk + g) ^ cx));
#pragma unroll
        for (int ni = 0; ni < 4; ni++)
#pragma unroll
            for (int kk = 0; kk < 2; kk++)
                b0[ni][kk] = *(const bfrag*)(bufB + (wn * 64 + ni * 16 + c) * 64
                                                  + 8 * ((4 * kk + g) ^ cx));
        asm volatile("s_waitcnt lgkmcnt(0)" ::: "memory");
        __builtin_amdgcn_sched_barrier(0);
        __builtin_amdgcn_s_setprio(1);
#pragma unroll
        for (int mi = 0; mi < 4; mi++)
#pragma unroll
            for (int ni = 0; ni < 4; ni++) {
                acc[mi][ni] = __builtin_amdgcn_mfma_f32_16x16x32_bf16(
                    a0[mi][0], b0[ni][0], acc[mi][ni], 0, 0, 0);
                acc[mi][ni] = __builtin_amdgcn_mfma_f32_16x16x32_bf16(
                    a0[mi][1], b0[ni][1], acc[mi][ni], 0, 0, 0);
            }
        __builtin_amdgcn_s_setprio(0);

        bfrag a1[4][2];
#pragma unroll
        for (int mi = 0; mi < 4; mi++)
#pragma unroll
            for (int kk = 0; kk < 2; kk++)
                a1[mi][kk] = *(const bfrag*)(bufA + (wm * 128 + (mi + 4) * 16 + c) * 64
                                                  + 8 * ((4 * kk + g) ^ cx));
        asm volatile("s_waitcnt lgkmcnt(0)" ::: "memory");
        __builtin_amdgcn_sched_barrier(0);
        __builtin_amdgcn_s_setprio(1);
#pragma unroll
        for (int mi = 0; mi < 4; mi++)
#pragma unroll
            for (int ni = 0; ni < 4; ni++) {
                acc[mi + 4][ni] = __builtin_amdgcn_mfma_f32_16x16x32_bf16(
                    a1[mi][0], b0[ni][0], acc[mi + 4][ni], 0, 0, 0);
                acc[mi + 4][ni] = __builtin_amdgcn_mfma_f32_16x16x32_bf16(
                    a1[mi][1], b0[ni][1], acc[mi + 4][ni], 0, 0, 0);
            }
        __builtin_amdgcn_s_setprio(0);

        __builtin_amdgcn_s_barrier();
        if (t + 2 < NT) {
            STAGE(t & 1, t + 2);
            asm volatile("s_waitcnt vmcnt(8)" ::: "memory");
        } else if (t + 1 < NT) {
            asm volatile("s_waitcnt vmcnt(0)" ::: "memory");
        }
        __builtin_amdgcn_s_barrier();
    }

#pragma unroll
    for (int mi = 0; mi < 8; mi++)
#pragma unroll
        for (int ni = 0; ni < 4; ni++) {
            long row = m0 + wm * 128 + mi * 16 + 4 * g;
            long col = n0 + wn * 64 + ni * 16 + c;
#pragma unroll
            for (int r = 0; r < 4; r++)
                stf(&C[(row + r) * N + col], acc[mi][ni][r]);
        }
}

// ---------------------------------------------------------------------------
// RoPE v2 + per-row L2 norm + sqk*sqrt(dm); QKVb bf16 layout [row][h*192+e].
// Block = (h, b, 64-wide t-tile); 4 waves x 16 rows. V staged in LDS [64][66]
// then written as 16 contiguous t-elems per thread -> coalesced Vt.
// Qb carries sdpa sqrt(dm)=32 AND log2e (exp2 path in attn).
// ---------------------------------------------------------------------------
__global__ __launch_bounds__(256)
void rope_norm_qk(const bf16* __restrict__ QKVb, const float* __restrict__ sqk,
                  bf16* __restrict__ Qb, bf16* __restrict__ Kb, bf16* __restrict__ Vt)
{
    __shared__ unsigned short vbuf[64][66];   // pad 66 -> <=4-way on gather

    int bid  = blockIdx.x;                // 0..2047
    int h    = bid >> 7;                  // / (B_*32)
    int rem  = bid & 127;
    int b    = rem >> 5;
    int tile = rem & 31;
    int w    = threadIdx.x >> 6;
    int lane = threadIdx.x & 63;

    int   j       = lane & 31;
    // inv_rev = 10000^(-j/32) / (2*pi);  log2(10000)/32 = 0.41524101
    float inv_rev = fexp2(-(float)j * 0.41524101f) * 0.15915494f;
    float se      = sqk[h * 64 + lane] * 32.f;   // sqk * sqrt(dm)

#pragma unroll 1
    for (int i = 0; i < 16; i++) {
        int tl = i * 4 + w;               // 0..63
        int t  = tile * 64 + tl;
        long row = (long)b * T_ + t;
        const bf16* base = QKVb + row * 3072 + h * 192;
        float q = ldf(base + lane);
        float k = ldf(base + 64 + lane);
        unsigned short vb = ((const unsigned short*)base)[128 + lane];

        float ar = (float)t * inv_rev;
        ar = ar - floorf(ar);                       // revolutions in [0,1)
        float s  = __builtin_amdgcn_sinf(ar);
        float cc = __builtin_amdgcn_cosf(ar);

        float qp = __shfl_xor(q, 32, 64);
        float kp = __shfl_xor(k, 32, 64);
        float sgn = (lane < 32) ? -1.f : 1.f;
        float qr = q * cc + sgn * qp * s;
        float kr = k * cc + sgn * kp * s;

        float qs = wave_sum(qr * qr);
        float ks = wave_sum(kr * kr);

        long idx = ((long)h * NROW + row) * 64 + lane;
        Qb[idx] = __float2bfloat16(qr * rsqrtf(qs) * se * EXPB);  // 32*log2e
        Kb[idx] = __float2bfloat16(kr * rsqrtf(ks) * se);
        vbuf[tl][lane] = vb;
    }
    __syncthreads();

    // V transpose write: thread -> (d = tid>>2, 16 t's at seg*16)
    int d   = threadIdx.x >> 2;
    int seg = threadIdx.x & 3;
    union { bfrag f; unsigned short s[8]; } o0, o1;
#pragma unroll
    for (int jj = 0; jj < 8; jj++) {
        o0.s[jj] = vbuf[seg * 16 + jj][d];
        o1.s[jj] = vbuf[seg * 16 + 8 + jj][d];
    }
    bf16* dst = Vt + ((long)(h * B_ + b) * 64 + d) * T_ + tile * 64 + seg * 16;
    *(bfrag*)dst       = o0.f;
    *(bfrag*)(dst + 8) = o1.f;
}

// ---------------------------------------------------------------------------
// MFMA flash attention, exp2 fixed-shift softmax (C-init = -EXPB), paired
// q-tiles. 8-wave blocks (512 thr), K/V LDS staging shared by 8 waves.
// Per-wave ranges differ by <=1 iteration (nA = 2*blk + (w>=4)); actA/actB
// guards wave-uniform. Heavy/light blk interleave; XCD swizzle.
// ---------------------------------------------------------------------------
__global__ __launch_bounds__(512)
void attn_mfma(const bf16* __restrict__ Qb, const bf16* __restrict__ Kb,
               const bf16* __restrict__ Vt, bf16* __restrict__ O)
{
    __shared__ bf16 kv[2][2][64 * 64];    // [buf][K|V][row*64 + chunk-swizzled]

    int orig   = blockIdx.x;              // 0..511
    int xcd    = orig & 7;
    int rest   = orig >> 3;               // 0..63
    int bh     = xcd * 8 + (rest & 7);    // 8 (b,h) per XCD -> 4MiB K/V in L2
    int blkraw = rest >> 3;               // 0..7
    int blk    = (blkraw & 1) ? (7 - (blkraw >> 1)) : (blkraw >> 1);
    int w      = threadIdx.x >> 6;        // 0..7
    int pr     = blk * 8 + w;             // 0..63
    int h = bh >> 2, b = bh & 3;

    int lane = threadIdx.x & 63;
    int g = lane >> 4, c = lane & 15;

    const bf16* kbase = Kb + ((long)h * NROW + (long)b * T_) * 64;
    const bf16* vbase = Vt + (long)(h * B_ + b) * 64 * (long)T_;

    int q0A = pr * 16, q0B = (127 - pr) * 16;
    const bf16* qbA = Qb + ((long)h * NROW + (long)b * T_ + q0A) * 64;
    const bf16* qbB = Qb + ((long)h * NROW + (long)b * T_ + q0B) * 64;
    bfrag qfA0 = *(const bfrag*)(qbA + (long)c * 64 + 8 * g);
    bfrag qfA1 = *(const bfrag*)(qbA + (long)c * 64 + 32 + 8 * g);
    bfrag qfB0 = *(const bfrag*)(qbB + (long)c * 64 + 8 * g);
    bfrag qfB1 = *(const bfrag*)(qbB + (long)c * 64 + 32 + 8 * g);

    const f4 CINIT = {-EXPB, -EXPB, -EXPB, -EXPB};

    f4 otA[4] = {{0,0,0,0},{0,0,0,0},{0,0,0,0},{0,0,0,0}};
    f4 otB[4] = {{0,0,0,0},{0,0,0,0},{0,0,0,0},{0,0,0,0}};
    float lA = 0.f, lB = 0.f;

    const int nA = pr >> 2;               // 2*blk + (w>=4)
    const int nB = 31 - nA;
    const int KTblk = 31 - 2 * blk;       // block-uniform loop bound (max nB)
    int qgA = q0A + c, qgB = q0B + c;

    const int srow8  = lane >> 3;                 // 0..7
    const int swz    = 8 * ((lane & 7) ^ srow8);  // swizzled source chunk

    auto STAGE = [&](int buf, int kt) {
        int k0 = kt * 64;
        int row = w * 8 + srow8;                  // 8 waves cover 64 rows
        gl_lds(kbase + (long)(k0 + row) * 64 + swz, &kv[buf][0][w * 8 * 64]);
        gl_lds(vbase + (long)row * T_ + k0 + swz,   &kv[buf][1][w * 8 * 64]);
    };

    STAGE(0, 0);
    __syncthreads();

    const int cx = c & 7;

    for (int kt = 0; kt <= KTblk; kt++) {
        int buf = kt & 1;
        if (kt < KTblk) STAGE(buf ^ 1, kt + 1);

        const bf16* Kl = &kv[buf][0][0];
        const bf16* Vl = &kv[buf][1][0];
        int k0 = kt * 64;
        bool actA = (kt <= nA);           // wave-uniform
        bool actB = (kt <= nB);           // wave-uniform
        unsigned wvA[8], wvB[8];

        if (actA || actB) {
#pragma unroll
            for (int kb = 0; kb < 4; kb++) {
                const bf16* kr = Kl + (16 * kb + c) * 64;
                bfrag ka = *(const bfrag*)(kr + 8 * (g ^ cx));
                bfrag kc = *(const bfrag*)(kr + 8 * ((g | 4) ^ cx));

                if (actB) {
                    f4 sB = __builtin_amdgcn_mfma_f32_16x16x32_bf16(ka, qfB0, CINIT, 0, 0, 0);
                    sB = __builtin_amdgcn_mfma_f32_16x16x32_bf16(kc, qfB1, sB, 0, 0, 0);
                    if (kt == nB) {
#pragma unroll
                        for (int r = 0; r < 4; r++)
                            if (k0 + 16 * kb + 4 * g + r > qgB) sB[r] = -1e30f;
                    }
                    float eB0 = fexp2(sB[0]), eB1 = fexp2(sB[1]);
                    float eB2 = fexp2(sB[2]), eB3 = fexp2(sB[3]);
                    lB += (eB0 + eB1) + (eB2 + eB3);
                    wvB[2 * kb]     = pk2t(eB0, eB1);
                    wvB[2 * kb + 1] = pk2t(eB2, eB3);
                }

                if (actA) {
                    f4 sA = __builtin_amdgcn_mfma_f32_16x16x32_bf16(ka, qfA0, CINIT, 0, 0, 0);
                    sA = __builtin_amdgcn_mfma_f32_16x16x32_bf16(kc, qfA1, sA, 0, 0, 0);
                    if (kt == nA) {
#pragma unroll
                        for (int r = 0; r < 4; r++)
                            if (k0 + 16 * kb + 4 * g + r > qgA) sA[r] = -1e30f;
                    }
                    float eA0 = fexp2(sA[0]), eA1 = fexp2(sA[1]);
                    float eA2 = fexp2(sA[2]), eA3 = fexp2(sA[3]);
                    lA += (eA0 + eA1) + (eA2 + eA3);
                    wvA[2 * kb]     = pk2t(eA0, eA1);
                    wvA[2 * kb + 1] = pk2t(eA2, eA3);
                }
            }

            // PV: two 32-key halves; B-frag = P^T via lane exchange; V from LDS
#pragma unroll
            for (int p = 0; p < 2; p++) {
                int s0l = c + 32 * (g & 1), s1l = s0l + 16;
                bool hi = (g >= 2);

                union { bfrag f; unsigned u[4]; } pfB, pfA;
                if (actB) {
                    unsigned Bb0 = (unsigned)__shfl((int)wvB[4 * p + 0], s0l, 64);
                    unsigned Bb1 = (unsigned)__shfl((int)wvB[4 * p + 1], s0l, 64);
                    unsigned Bb2 = (unsigned)__shfl((int)wvB[4 * p + 2], s0l, 64);
                    unsigned Bb3 = (unsigned)__shfl((int)wvB[4 * p + 3], s0l, 64);
                    unsigned Bb4 = (unsigned)__shfl((int)wvB[4 * p + 0], s1l, 64);
                    unsigned Bb5 = (unsigned)__shfl((int)wvB[4 * p + 1], s1l, 64);
                    unsigned Bb6 = (unsigned)__shfl((int)wvB[4 * p + 2], s1l, 64);
                    unsigned Bb7 = (unsigned)__shfl((int)wvB[4 * p + 3], s1l, 64);
                    pfB.u[0] = hi ? Bb2 : Bb0;
                    pfB.u[1] = hi ? Bb3 : Bb1;
                    pfB.u[2] = hi ? Bb6 : Bb4;
                    pfB.u[3] = hi ? Bb7 : Bb5;
                }
                if (actA) {
                    unsigned Ab0 = (unsigned)__shfl((int)wvA[4 * p + 0], s0l, 64);
                    unsigned Ab1 = (unsigned)__shfl((int)wvA[4 * p + 1], s0l, 64);
                    unsigned Ab2 = (unsigned)__shfl((int)wvA[4 * p + 2], s0l, 64);
                    unsigned Ab3 = (unsigned)__shfl((int)wvA[4 * p + 3], s0l, 64);
                    unsigned Ab4 = (unsigned)__shfl((int)wvA[4 * p + 0], s1l, 64);
                    unsigned Ab5 = (unsigned)__shfl((int)wvA[4 * p + 1], s1l, 64);
                    unsigned Ab6 = (unsigned)__shfl((int)wvA[4 * p + 2], s1l, 64);
                    unsigned Ab7 = (unsigned)__shfl((int)wvA[4 * p + 3], s1l, 64);
                    pfA.u[0] = hi ? Ab2 : Ab0;
                    pfA.u[1] = hi ? Ab3 : Ab1;
                    pfA.u[2] = hi ? Ab6 : Ab4;
                    pfA.u[3] = hi ? Ab7 : Ab5;
                }

#pragma unroll
                for (int dblk = 0; dblk < 4; dblk++) {
                    bfrag vf = *(const bfrag*)(Vl + (16 * dblk + c) * 64
                                                  + 8 * (((p << 2) | g) ^ cx));
                    if (actB)
                        otB[dblk] = __builtin_amdgcn_mfma_f32_16x16x32_bf16(vf, pfB.f, otB[dblk], 0, 0, 0);
                    if (actA)
                        otA[dblk] = __builtin_amdgcn_mfma_f32_16x16x32_bf16(vf, pfA.f, otA[dblk], 0, 0, 0);
                }
            }
        }
        __syncthreads();
    }

    lA += __shfl_xor(lA, 16, 64); lA += __shfl_xor(lA, 32, 64);
    lB += __shfl_xor(lB, 16, 64); lB += __shfl_xor(lB, 32, 64);

    float invA = 1.f / lA, invB = 1.f / lB;
    long orowA = (long)(b * T_ + q0A + c) * DM + h * 64;
    long orowB = (long)(b * T_ + q0B + c) * DM + h * 64;
#pragma unroll
    for (int dblk = 0; dblk < 4; dblk++)
#pragma unroll
        for (int r = 0; r < 4; r++) {
            O[orowA + 16 * dblk + 4 * g + r] = __float2bfloat16(otA[dblk][r] * invA);
            O[orowB + 16 * dblk + 4 * g + r] = __float2bfloat16(otB[dblk][r] * invB);
        }
}

// ---------------------------------------------------------------------------
// Out = justnorm(A + lr*(Bn - A)); t-input = Tt (+ Tt2 if non-null, summed).
// Vectorized: thread handles 4 contiguous elems at tid*4.
// ---------------------------------------------------------------------------
template <typename TX, typename TT>
__global__ __launch_bounds__(256)
void lerp_norm(const TX* __restrict__ X, const TT* __restrict__ Tt,
               const TT* __restrict__ Tt2, const float* __restrict__ alpha,
               float ascale, float* __restrict__ OutF, bf16* __restrict__ OutB)
{
    long row = blockIdx.x;
    int t4 = threadIdx.x * 4;
    const TX* xr = X  + row * DM + t4;
    const TT* tr = Tt + row * DM + t4;

    float xs[4], ts[4];
    ld4(xr, xs);
    ld4(tr, ts);
    if (Tt2) {
        float t2[4];
        ld4(Tt2 + row * DM + t4, t2);
#pragma unroll
        for (int i = 0; i < 4; i++) ts[i] += t2[i];
    }
    float sx = 0.f, st = 0.f;
#pragma unroll
    for (int i = 0; i < 4; i++) { sx += xs[i] * xs[i]; st += ts[i] * ts[i]; }
    sx = block_sum(sx);
    st = block_sum(st);
    float ix = rsqrtf(sx), it = rsqrtf(st);

    float4 al = *(const float4*)(alpha + t4);
    float av[4] = {al.x, al.y, al.z, al.w};
    float ys[4], sy = 0.f;
#pragma unroll
    for (int i = 0; i < 4; i++) {
        float a  = xs[i] * ix;
        float bn = ts[i] * it;
        float lr = fabsf(av[i] * ascale);
        ys[i] = a + lr * (bn - a);
        sy += ys[i] * ys[i];
    }
    sy = block_sum(sy);
    float iy = rsqrtf(sy);
#pragma unroll
    for (int i = 0; i < 4; i++) ys[i] *= iy;

    if (OutF) *(float4*)(OutF + row * DM + t4) = make_float4(ys[0], ys[1], ys[2], ys[3]);
    if (OutB) {
        uint2 o;
        o.x = pk2(ys[0], ys[1]);
        o.y = pk2(ys[2], ys[3]);
        *(uint2*)(OutB + row * DM + t4) = o;
    }
}

// ---------------------------------------------------------------------------
// tn = justnorm(suv*32*uv_row[8192]); res = u*silu(v), written IN PLACE into
// cols 0..4096 of the same uv row (each thread writes only cols it read;
// all reads precede writes). One block per row, 8192 blocks.
// ---------------------------------------------------------------------------
__global__ __launch_bounds__(256)
void mlp_act(bf16* __restrict__ UV, const float* __restrict__ suv)
{
    long row = blockIdx.x;
    bf16* ur = UV + row * 8192;
    int t8 = threadIdx.x * 8;

    float f[4][8];
    float ss = 0.f;
#pragma unroll
    for (int ch = 0; ch < 4; ch++) {
        bfrag d = *(const bfrag*)(ur + ch * 2048 + t8);
        const float4* sp = (const float4*)(suv + ch * 2048 + t8);
        float4 s0 = sp[0], s1 = sp[1];
        float sv[8] = {s0.x, s0.y, s0.z, s0.w, s1.x, s1.y, s1.z, s1.w};
#pragma unroll
        for (int e = 0; e < 8; e++) {
            unsigned short us = __builtin_bit_cast(unsigned short, (short)d[e]);
            float v = __builtin_bit_cast(float, (unsigned)us << 16) * sv[e] * 32.f;
            f[ch][e] = v;
            ss += v * v;
        }
    }
    ss = block_sum(ss);
    float inv = rsqrtf(ss);

#pragma unroll
    for (int ch = 0; ch < 2; ch++) {
        union { bfrag f; unsigned u[4]; } o;
#pragma unroll
        for (int e = 0; e < 8; e += 2) {
            float u0 = f[ch][e]     * inv, u1 = f[ch][e + 1]     * inv;
            float v0 = f[ch + 2][e] * inv, v1 = f[ch + 2][e + 1] * inv;
            float r0 = u0 * v0 / (1.f + __expf(-v0));
            float r1 = u1 * v1 / (1.f + __expf(-v1));
            o.u[e >> 1] = pk2(r0, r1);
        }
        *(bfrag*)(ur + ch * 2048 + t8) = o.f;
    }
}

// ---------------------------------------------------------------------------
extern "C" void kernel_launch(void* const* d_in, const int* in_sizes, int n_in,
                              void* d_out, int out_size, void* d_ws, size_t ws_size,
                              hipStream_t stream)
{
    const float* x          = (const float*)d_in[0];
    const float* qkv_w      = (const float*)d_in[1];
    const float* sqk        = (const float*)d_in[2];
    const float* W_O        = (const float*)d_in[3];
    const float* Wu         = (const float*)d_in[4];
    const float* Wv         = (const float*)d_in[5];
    const float* attn_alpha = (const float*)d_in[6];
    const float* mlp_alpha  = (const float*)d_in[7];
    const float* suv        = (const float*)d_in[8];
    float* out = (float*)d_out;

    const long MiB = 1048576;
    char* ws = (char*)d_ws;
    bf16*  Wub   = (bf16*) (ws + 0 * MiB);    // 16MB (step0 -> step6)
    bf16*  Wvb   = (bf16*) (ws + 16 * MiB);   // 8MB  (step0 -> step8)
    bf16*  x1b   = (bf16*) (ws + 32 * MiB);   // (step5 -> step6, step9)
    bf16*  QKVb  = (bf16*) (ws + 48 * MiB);   // (step1 -> step2)
    bf16*  tbuf  = (bf16*) (ws + 48 * MiB);   // (step4 -> step5)
    bf16*  uv    = (bf16*) (ws + 48 * MiB);   // [8192][8192] (step6 -> step8)
    bf16*  xb    = (bf16*) (ws + 144 * MiB);  // (step0 -> step1; Qb aliases)
    bf16*  Qb    = (bf16*) (ws + 144 * MiB);  // (step2 -> step3)
    bf16*  Kb    = (bf16*) (ws + 160 * MiB);  // (step2 -> step3)
    bf16*  Vt    = (bf16*) (ws + 176 * MiB);  // (step2 -> step3)
    bf16*  t2a   = (bf16*) (ws + 176 * MiB);  // (step8 -> step9; Vt dead)
    bf16*  qkvwb = (bf16*) (ws + 192 * MiB);  // (step0 -> step1)
    bf16*  attno = (bf16*) (ws + 192 * MiB);  // (step3 -> step4)
    bf16*  t2b   = (bf16*) (ws + 192 * MiB);  // (step8 -> step9; attno dead)
    bf16*  Wob   = (bf16*) (ws + 208 * MiB);  // (step0 -> step4)
    // peak 210 MiB

    // 0) ALL f32->bf16 converts in one fused launch
    convert_all_k<<<12288, 256, 0, stream>>>(x, xb, qkv_w, qkvwb, W_O, Wob,
                                             Wu, Wub, Wv, Wvb);

    // 1) QKV projection -> bf16 [8192][3072]  (256^2 pipelined gemm)
    gemm_bf16_256<bf16><<<dim3(12, 32, 1), 512, 0, stream>>>(
        xb, qkvwb, QKVb, NROW, 3072, DM, DM, DM, 0L);

    // 2) RoPE v2 + justnorm + scaling -> Qb/Kb/Vt (coalesced Vt via LDS)
    rope_norm_qk<<<H_ * B_ * (T_ / 64), 256, 0, stream>>>(QKVb, sqk, Qb, Kb, Vt);

    // 3) MFMA flash attention (8-wave blocks) -> attno bf16
    attn_mfma<<<512, 512, 0, stream>>>(Qb, Kb, Vt, attno);

    // 4) W_O projection -> tbuf bf16 (128^2 kernel; QKVb region dead)
    gemm_bf16<bf16><<<dim3(8, 64), 256, 0, stream>>>(attno, Wob, tbuf, NROW, DM, DM);

    // 5) attention residual lerp-norm -> x1b (A from pristine fp32 x)
    lerp_norm<float, bf16><<<NROW, 256, 0, stream>>>(
        x, tbuf, (const bf16*)nullptr, attn_alpha, 1.6f, (float*)nullptr, x1b);

    // 6) uv = x1b @ Wu^T, full M in ONE dispatch (tbuf/Qb/Kb all dead)
    gemm_bf16_256<bf16><<<dim3(32, 32, 1), 512, 0, stream>>>(
        x1b, Wub, uv, NROW, 8 * DM, DM, DM, DM, 0L);

    // 7) act in place: res = u*silu(v) -> uv cols 0..4096 (row stride 8192)
    mlp_act<<<NROW, 256, 0, stream>>>(uv, suv);

    // 8) t2 = res @ Wv^T, split-K=2 -> bf16 partials (LDA=8192, LDB=4096;
    //    t2a@176MiB over dead Vt, t2b@192MiB over dead attno)
    gemm_bf16_256<bf16><<<dim3(4, 32, 2), 512, 0, stream>>>(
        uv, Wvb, t2a, NROW, DM, 2048, 8192, 4096, 8388608L);

    // 9) MLP residual lerp-norm -> out (t = t2a + t2b)
    lerp_norm<bf16, bf16><<<NROW, 256, 0, stream>>>(
        x1b, t2a, t2b, mlp_alpha, 0.05f, out, (bf16*)nullptr);
}